// Round 10
// baseline (364.904 us; speedup 1.0000x reference)
//
#include <hip/hip_runtime.h>
#include <hip/hip_bf16.h>
#include <stdint.h>

#define B_    4
#define N_    256
#define C_    256
#define FH_   100
#define FW_   152
#define P_HW  (FH_*FW_)      // 15200
#define NCLS  91
#define CAND  23040          // N_*90
#define DIN   12544
#define PRE   1024

typedef unsigned long long u64;
typedef unsigned int u32;
typedef unsigned short u16;
typedef __attribute__((ext_vector_type(8))) _Float16 half8;
typedef __attribute__((ext_vector_type(8))) short short8;
typedef __attribute__((ext_vector_type(4))) float f32x4;

__device__ inline u16 h2bits(_Float16 h) { return *reinterpret_cast<u16*>(&h); }

// split v (already prescaled) into fp16 h0 + h1, exact-residual style
__device__ inline void split2(float v, u16& b0, u16& b1) {
  _Float16 h0 = (_Float16)v;
  float r = v - (float)h0;
  _Float16 h1 = (_Float16)r;
  b0 = h2bits(h0); b1 = h2bits(h1);
}

__device__ inline void gload_lds16(const void* g, void* l) {
  __builtin_amdgcn_global_load_lds(
      (const __attribute__((address_space(1))) void*)g,
      (__attribute__((address_space(3))) void*)l, 16, 0, 0);
}

// ---------------- feature transpose (B,C,H,W) -> (B,H,W,C) ----------------
__global__ void k_transpose(const float* __restrict__ in, float* __restrict__ out) {
  __shared__ float t[32][33];
  int b  = blockIdx.z;
  int c0 = blockIdx.y * 32;
  int p0 = blockIdx.x * 32;
  int tx = threadIdx.x & 31, ty = threadIdx.x >> 5;
  const float* inb = in  + (size_t)b * C_ * P_HW;
  float*       ob  = out + (size_t)b * P_HW * C_;
  #pragma unroll
  for (int q = 0; q < 4; q++)
    t[ty + q*8][tx] = inb[(size_t)(c0 + ty + q*8) * P_HW + p0 + tx];
  __syncthreads();
  #pragma unroll
  for (int q = 0; q < 4; q++)
    ob[(size_t)(p0 + ty + q*8) * C_ + c0 + tx] = t[tx][ty + q*8];
}

// ------- roi align -> Xt [2 planes][DIN/8][1024 rows][8] fp16 of (X*16) ----
__global__ __launch_bounds__(256, 8) void k_roialign(const float* __restrict__ featT,
                                                     const float* __restrict__ props,
                                                     u16* __restrict__ Xs) {
  __shared__ float sPW[196][8];     // {p00,p01,p10,p11,w00,w01,w10,w11}
  __shared__ float cellv[32][51];   // [ch-in-group][cell]
  int bid = blockIdx.x;
  int xcd = bid & 7;
  int b = xcd >> 1;
  int n = ((bid >> 3) << 1) | (xcd & 1);
  int r = (b << 8) | n;                 // bijective 0..1023, XCD-batch affine
  int tid = threadIdx.x;

  float x1 = props[r*4+0], y1 = props[r*4+1];
  float x2 = props[r*4+2], y2 = props[r*4+3];
  float x1s = x1 * 0.125f, y1s = y1 * 0.125f;
  float x2s = x2 * 0.125f, y2s = y2 * 0.125f;
  float rw = fmaxf(x2s - x1s, 1.0f);
  float rh = fmaxf(y2s - y1s, 1.0f);
  float rwd = rw / 7.0f, rhd = rh / 7.0f;

  if (tid < 196) {
    int cell = tid >> 2, s = tid & 3;
    int py = cell / 7, px = cell % 7;
    int sy = s >> 1, sx = s & 1;
    float gqy = (float)py + 0.25f + 0.5f * (float)sy;
    float gqx = (float)px + 0.25f + 0.5f * (float)sx;
    float gy = fminf(fmaxf(y1s + rhd * gqy, 0.0f), 99.0f);
    float gx = fminf(fmaxf(x1s + rwd * gqx, 0.0f), 151.0f);
    float y0f = floorf(gy), x0f = floorf(gx);
    float ly = gy - y0f, lx = gx - x0f;
    int y0i = (int)y0f;
    int y1i = (int)fminf(y0f + 1.0f, 99.0f);
    int x0i = (int)x0f;
    int x1i = (int)fminf(x0f + 1.0f, 151.0f);
    sPW[tid][0] = __int_as_float((y0i * FW_ + x0i) * 256);
    sPW[tid][1] = __int_as_float((y0i * FW_ + x1i) * 256);
    sPW[tid][2] = __int_as_float((y1i * FW_ + x0i) * 256);
    sPW[tid][3] = __int_as_float((y1i * FW_ + x1i) * 256);
    sPW[tid][4] = (1.f-ly)*(1.f-lx);
    sPW[tid][5] = (1.f-ly)*lx;
    sPW[tid][6] = ly*(1.f-lx);
    sPW[tid][7] = ly*lx;
  }
  __syncthreads();

  int c32 = tid & 31;
  int slot = tid >> 5;
  const size_t PLS = (size_t)(DIN/8) * 1024 * 8;

  for (int g = 0; g < 8; g++) {
    const float* fb = featT + (size_t)b * P_HW * C_ + g*32 + c32;
    for (int cell = slot; cell < 49; cell += 8) {
      float acc = 0.f;
      #pragma unroll
      for (int s = 0; s < 4; s++) {
        int cs = cell*4 + s;
        float4 pv = *(const float4*)&sPW[cs][0];
        float4 wv = *(const float4*)&sPW[cs][4];
        acc += wv.x * fb[__float_as_int(pv.x)]
             + wv.y * fb[__float_as_int(pv.y)]
             + wv.z * fb[__float_as_int(pv.z)]
             + wv.w * fb[__float_as_int(pv.w)];
      }
      cellv[c32][cell] = acc * 4.0f;   // 0.25 (avg) * 16 (prescale)
    }
    __syncthreads();
    if (tid < 196) {
      short8 v0, v1;
      #pragma unroll
      for (int e = 0; e < 8; e++) {
        int kl = tid*8 + e;
        int chl = kl / 49;
        int cell = kl - chl*49;
        float v = cellv[chl][cell];
        u16 h0, h1;
        split2(v, h0, h1);
        v0[e] = (short)h0; v1[e] = (short)h1;
      }
      size_t cg = (size_t)g*196 + tid;
      size_t base = (cg * 1024 + r) * 8;
      *reinterpret_cast<short8*>(Xs + base)       = v0;
      *reinterpret_cast<short8*>(Xs + PLS + base) = v1;
    }
    __syncthreads();
  }
}

// -------- MFMA GEMM, fp32 via fp16 2-plane 3-pass (a0b0+a1b0+a0b1) --------
// 128x128 tile, 8 waves (2x4), wave tile 64x32.
// 4-buffer LDS pipeline (T3/T4): 3 stages in flight, counted vmcnt, never
// drained to 0 in the main loop. 128KB LDS -> 1 block/CU; overlap is
// intra-block (stage s+3 issues while compute(s) runs).
__global__ __launch_bounds__(512) void k_gemm_f16(
    const u16* __restrict__ As, const float* __restrict__ Bw,
    float* __restrict__ part, int kg, int nsteps, int nct, int outw,
    size_t sstride) {
  __shared__ __align__(16) char lds[131072];   // 4 x (A 16KB + B 16KB)
  int tid = threadIdx.x;
  int wid = tid >> 6, lane = tid & 63;
  int l15 = lane & 15, lq = lane >> 4;
  int bid = blockIdx.x;
  int z = bid & 7, xy = bid >> 3;              // one K-slice per XCD
  int col0 = (xy % nct) * 128, row0 = (xy / nct) * 128;
  int wr = wid >> 2, wc = wid & 3;             // 8 waves: 2 row x 4 col, 64x32
  int kbase0 = z * nsteps * 32;

  auto STAGE = [&](int s, int bsel) {
    int kb = kbase0 + s * 32;
    char* dst = lds + (size_t)bsel * 32768;
    #pragma unroll
    for (int j = 0; j < 4; j++) {
      int cid = tid + j*512;
      const char* src;
      if (j < 2) {
        int pl = cid >> 9;
        int kc = (cid >> 7) & 3, rr = cid & 127;
        src = (const char*)(As + ((size_t)(pl*kg + (kb>>3) + kc)*1024 + row0 + rr)*8);
      } else {
        int cid2 = cid - 1024;
        int kk = cid2 >> 5, c4 = cid2 & 31;
        int col = (c4*4) ^ (((kk >> 3) & 1) << 4);
        src = (const char*)(Bw + (size_t)(kb + kk)*outw + col0 + col);
      }
      gload_lds16(src, dst + (size_t)cid*16);
    }
  };

  f32x4 acc[4][2];
  #pragma unroll
  for (int i = 0; i < 4; i++)
    #pragma unroll
    for (int j = 0; j < 2; j++)
      #pragma unroll
      for (int q = 0; q < 4; q++) acc[i][j][q] = 0.f;

  STAGE(0, 0);
  if (nsteps > 1) STAGE(1, 1);
  if (nsteps > 2) STAGE(2, 2);
  for (int s = 0; s < nsteps; s++) {
    // wait for stage s only: stages s+1, s+2 (4 loads each) stay in flight
    if (s + 2 < nsteps)      asm volatile("s_waitcnt vmcnt(8)" ::: "memory");
    else if (s + 1 < nsteps) asm volatile("s_waitcnt vmcnt(4)" ::: "memory");
    else                     asm volatile("s_waitcnt vmcnt(0)" ::: "memory");
    __builtin_amdgcn_s_barrier();
    __builtin_amdgcn_sched_barrier(0);   // no LDS reads above the barrier

    // issue the stage 3 steps ahead; its buffer was last read at iter s-1
    // (two barriers ago), so it is free. Loads overlap this step's compute.
    if (s + 3 < nsteps) STAGE(s + 3, (s + 3) & 3);

    int cur = s & 3;
    const u16*   Alds = (const u16*)(lds + (size_t)cur * 32768);
    const float* Blds = (const float*)(lds + (size_t)cur * 32768 + 16384);

    __builtin_amdgcn_s_setprio(1);
    half8 af[2][4];
    #pragma unroll
    for (int pl = 0; pl < 2; pl++)
      #pragma unroll
      for (int fr = 0; fr < 4; fr++) {
        int chunk = (pl*4 + lq)*128 + wr*64 + fr*16 + l15;
        af[pl][fr] = *reinterpret_cast<const half8*>(&Alds[(size_t)chunk*8]);
      }
    int cxor = (lq & 1) << 4;
    #pragma unroll
    for (int fc = 0; fc < 2; fc++) {
      int colx = (wc*32 + fc*16 + l15) ^ cxor;
      half8 b0, b1;
      #pragma unroll
      for (int j = 0; j < 8; j++) {
        float w = Blds[(lq*8 + j)*128 + colx] * 128.0f;
        _Float16 h0 = (_Float16)w;
        float rres = w - (float)h0;
        b0[j] = h0; b1[j] = (_Float16)rres;
      }
      #pragma unroll
      for (int fr = 0; fr < 4; fr++) {
        acc[fr][fc] = __builtin_amdgcn_mfma_f32_16x16x32_f16(af[0][fr], b0, acc[fr][fc], 0, 0, 0);
        acc[fr][fc] = __builtin_amdgcn_mfma_f32_16x16x32_f16(af[1][fr], b0, acc[fr][fc], 0, 0, 0);
        acc[fr][fc] = __builtin_amdgcn_mfma_f32_16x16x32_f16(af[0][fr], b1, acc[fr][fc], 0, 0, 0);
      }
    }
    __builtin_amdgcn_s_setprio(0);
    // all LDS reads of cur buf must complete before its next overwrite
    __builtin_amdgcn_sched_barrier(0);
    asm volatile("s_waitcnt lgkmcnt(0)" ::: "memory");
    __builtin_amdgcn_s_barrier();
  }

  float* pp = part + (size_t)z * sstride;
  #pragma unroll
  for (int fr = 0; fr < 4; fr++)
    #pragma unroll
    for (int fc = 0; fc < 2; fc++) {
      int col = col0 + wc*32 + fc*16 + l15;
      #pragma unroll
      for (int rr = 0; rr < 4; rr++) {
        int row = row0 + wr*64 + fr*16 + lq*4 + rr;
        pp[(size_t)row*outw + col] = acc[fr][fc][rr];
      }
    }
}

// -------- reduce split-K -> tiled fp16 planes (coalesced reads) ------------
__global__ void k_reduce_split(const float* __restrict__ part,
                               const float* __restrict__ bias,
                               u16* __restrict__ ys) {
  int idx = blockIdx.x * 256 + threadIdx.x;   // 131072 = 1024 rows * 128 cg
  int row = idx >> 7, cg = idx & 127;
  float4 s0 = {0,0,0,0}, s1 = {0,0,0,0};
  #pragma unroll
  for (int s = 0; s < 8; s++) {
    const float4* p = (const float4*)(part + (size_t)s*1048576 + (size_t)row*1024 + cg*8);
    float4 a = p[0], b = p[1];
    s0.x += a.x; s0.y += a.y; s0.z += a.z; s0.w += a.w;
    s1.x += b.x; s1.y += b.y; s1.z += b.z; s1.w += b.w;
  }
  float v[8] = {s0.x, s0.y, s0.z, s0.w, s1.x, s1.y, s1.z, s1.w};
  short8 o0, o1;
  #pragma unroll
  for (int e = 0; e < 8; e++) {
    float x = v[e] * (1.0f/2048.0f) + bias[cg*8 + e];
    x = fmaxf(x, 0.f) * 16.0f;                // prescale for next layer
    u16 h0, h1;
    split2(x, h0, h1);
    o0[e] = (short)h0; o1[e] = (short)h1;
  }
  size_t base = ((size_t)cg * 1024 + row) * 8;   // kg = 128 for K=1024
  *reinterpret_cast<short8*>(ys + base)               = o0;
  *reinterpret_cast<short8*>(ys + (size_t)1048576 + base) = o1;
}

// -------- pack Wc|Wb -> Wcat [1024][512] fp32 (pad 455..511 = 0), bcat -----
__global__ void k_packW(const float* __restrict__ Wc, const float* __restrict__ Wb,
                        const float* __restrict__ bc, const float* __restrict__ bb,
                        float* __restrict__ Wcat, float* __restrict__ bcat) {
  int idx = blockIdx.x * 256 + threadIdx.x;   // 524288
  int k = idx >> 9, col = idx & 511;
  float v = 0.f;
  if (col < 91)       v = Wc[(size_t)k*91 + col];
  else if (col < 455) v = Wb[(size_t)k*364 + (col - 91)];
  Wcat[idx] = v;
  if (idx < 512) {
    float bv = 0.f;
    if (idx < 91)       bv = bc[idx];
    else if (idx < 455) bv = bb[idx - 91];
    bcat[idx] = bv;
  }
}

// -------- heads reduce: sum 8 slices, +bcat, scatter to logits/deltas ------
__global__ void k_reduce_heads(const float* __restrict__ part,
                               const float* __restrict__ bcat,
                               float* __restrict__ logits,
                               float* __restrict__ deltas) {
  int idx = blockIdx.x * 256 + threadIdx.x;   // 524288 = 1024 * 512
  int row = idx >> 9, col = idx & 511;
  float v = 0.f;
  #pragma unroll
  for (int s = 0; s < 8; s++) v += part[idx + (size_t)s*524288];
  v = v * (1.0f/2048.0f) + bcat[col];
  if (col < 91)       logits[(size_t)row*91 + col] = v;
  else if (col < 455) deltas[(size_t)row*364 + (col - 91)] = v;
}

// -------- softmax + box decode + candidate keys ----------------------------
__global__ void k_decode(const float* __restrict__ logits,
                         const float* __restrict__ deltas,
                         const float* __restrict__ props,
                         float* __restrict__ cboxes,
                         u64* __restrict__ keys) {
  int r = blockIdx.x;
  int j = threadIdx.x;   // 128
  __shared__ float red[128];
  float lg = (j < NCLS) ? logits[r*NCLS + j] : -3.4e38f;
  red[j] = lg;
  __syncthreads();
  for (int s = 64; s > 0; s >>= 1) {
    if (j < s) red[j] = fmaxf(red[j], red[j+s]);
    __syncthreads();
  }
  float mx = red[0];
  __syncthreads();
  float e = (j < NCLS) ? expf(lg - mx) : 0.f;
  red[j] = e;
  __syncthreads();
  for (int s = 64; s > 0; s >>= 1) {
    if (j < s) red[j] += red[j+s];
    __syncthreads();
  }
  float p = e / red[0];
  if (j >= 1 && j < NCLS) {
    float px1 = props[r*4+0], py1 = props[r*4+1];
    float px2 = props[r*4+2], py2 = props[r*4+3];
    float w = px2 - px1, h = py2 - py1;
    float cx = px1 + 0.5f*w, cy = py1 + 0.5f*h;
    float d0 = deltas[r*364 + j*4 + 0];
    float d1 = deltas[r*364 + j*4 + 1];
    float d2 = deltas[r*364 + j*4 + 2];
    float d3 = deltas[r*364 + j*4 + 3];
    float dx = d0 / 10.0f, dy = d1 / 10.0f;
    float dw = fminf(d2 / 5.0f, 4.135166556742356f);
    float dh = fminf(d3 / 5.0f, 4.135166556742356f);
    float pcx = dx*w + cx, pcy = dy*h + cy;
    float pw = expf(dw)*w, ph = expf(dh)*h;
    float bx1 = fminf(fmaxf(pcx - 0.5f*pw, 0.f), 1216.f);
    float by1 = fminf(fmaxf(pcy - 0.5f*ph, 0.f),  800.f);
    float bx2 = fminf(fmaxf(pcx + 0.5f*pw, 0.f), 1216.f);
    float by2 = fminf(fmaxf(pcy + 0.5f*ph, 0.f),  800.f);
    bool valid = (p > 0.05f) && ((bx2 - bx1) >= 0.01f) && ((by2 - by1) >= 0.01f);
    int b = r >> 8, n = r & 255;
    int cidx = n*90 + (j-1);
    size_t cb = (size_t)b*CAND + cidx;
    cboxes[cb*4+0] = bx1; cboxes[cb*4+1] = by1;
    cboxes[cb*4+2] = bx2; cboxes[cb*4+3] = by2;
    u64 key = 0ull;
    if (valid)
      key = (((u64)__float_as_uint(p)) << 32) | (u32)(~(u32)cidx);
    keys[cb] = key;
  }
}

// -------- per (batch,half): compact valid + bitonic sort desc, top1024 -----
#define SORTN 4096
__global__ __launch_bounds__(1024) void k_sort(const u64* __restrict__ keys,
                                               u64* __restrict__ sorted) {
  __shared__ u64 sk[SORTN];
  __shared__ int cnt;
  int t = threadIdx.x;
  int b = blockIdx.x >> 1, h = blockIdx.x & 1;
  if (t == 0) cnt = 0;
  __syncthreads();
  const u64* kb = keys + (size_t)b*CAND + (size_t)h*(CAND/2);
  for (int q = 0; q < 12; q++) {
    int idx = t + q*1024;
    if (idx < CAND/2) {
      u64 k = kb[idx];
      if (k) { int pos = atomicAdd(&cnt, 1); sk[pos] = k; }
    }
  }
  __syncthreads();
  int total = cnt;
  for (int s = t; s < SORTN; s += 1024)
    if (s >= total) sk[s] = 0ull;
  __syncthreads();
  for (int k = 2; k <= SORTN; k <<= 1) {
    for (int jj = k >> 1; jj > 0; jj >>= 1) {
      for (int i = t; i < SORTN; i += 1024) {
        int ixj = i ^ jj;
        if (ixj > i) {
          u64 a = sk[i], bb = sk[ixj];
          bool up = ((i & k) == 0);
          if (up ? (a < bb) : (a > bb)) { sk[i] = bb; sk[ixj] = a; }
        }
      }
      __syncthreads();
    }
  }
  sorted[((size_t)b*2 + h)*1024 + t] = sk[t];
}

// -------- per batch: merge halves, tiled greedy NMS, emit final 100 --------
__global__ __launch_bounds__(1024) void k_nms(const u64* __restrict__ sorted,
                                              const float* __restrict__ cboxes,
                                              float* __restrict__ out) {
  __shared__ u64 m[2048];
  __shared__ float sX1[1024], sY1[1024], sX2[1024], sY2[1024], sAR[1024];
  __shared__ int keepL[1024];
  __shared__ int wsum[16];
  int t = threadIdx.x;
  int b = blockIdx.x;
  m[t]        = sorted[((size_t)b*2 + 0)*1024 + t];
  m[2047 - t] = sorted[((size_t)b*2 + 1)*1024 + t];
  __syncthreads();
  for (int lg = 10; lg >= 0; lg--) {
    int jj = 1 << lg;
    int pos = ((t >> lg) << (lg+1)) + (t & (jj-1));
    u64 a = m[pos], bb = m[pos + jj];
    if (a < bb) { m[pos] = bb; m[pos + jj] = a; }
    __syncthreads();
  }
  u64 key = m[t];
  bool valid = key != 0ull;
  float score = __uint_as_float((u32)(key >> 32));
  u32 cidx = ~((u32)(key & 0xFFFFFFFFu));
  int label = valid ? (int)(cidx % 90u) + 1 : 0;
  float cb0 = 0.f, cb1 = 0.f, cb2 = 0.f, cb3 = 0.f;
  if (valid) {
    size_t cb = ((size_t)b*CAND + cidx) * 4;
    cb0 = cboxes[cb+0]; cb1 = cboxes[cb+1];
    cb2 = cboxes[cb+2]; cb3 = cboxes[cb+3];
  }
  float off = (float)label * 1218.0f;
  float ox1 = cb0 + off, oy1 = cb1 + off;
  float ox2 = cb2 + off, oy2 = cb3 + off;
  float area = (ox2 - ox1) * (oy2 - oy1);
  sX1[t] = ox1; sY1[t] = oy1; sX2[t] = ox2; sY2[t] = oy2; sAR[t] = area;
  keepL[t] = valid ? 1 : 0;
  __syncthreads();

  int wid = t >> 6, lane = t & 63;
  for (int tile = 0; tile < 16; tile++) {
    if (wid == 0) {
      int idx = tile*64 + lane;
      bool kp = keepL[idx] != 0;
      float bx1 = sX1[idx], by1 = sY1[idx], bx2 = sX2[idx], by2 = sY2[idx], ba = sAR[idx];
      u64 alive = __ballot(kp);
      #pragma unroll 1
      for (int i = 0; i < 63; i++) {
        if ((alive >> i) & 1ull) {
          int ii = tile*64 + i;
          float ltx = fmaxf(sX1[ii], bx1), lty = fmaxf(sY1[ii], by1);
          float rbx = fminf(sX2[ii], bx2), rby = fminf(sY2[ii], by2);
          float iw = fmaxf(rbx - ltx, 0.f), ih = fmaxf(rby - lty, 0.f);
          float inter = iw * ih;
          float iou = inter / (sAR[ii] + ba - inter + 1e-9f);
          if (lane > i && iou > 0.5f) kp = false;
        }
        alive = __ballot(kp);
      }
      keepL[idx] = kp ? 1 : 0;
    }
    __syncthreads();
    if (t >= (tile+1)*64) {
      bool kp = keepL[t] != 0;
      if (kp) {
        #pragma unroll 1
        for (int i = tile*64; i < tile*64 + 64; i++) {
          if (keepL[i]) {
            float ltx = fmaxf(sX1[i], ox1), lty = fmaxf(sY1[i], oy1);
            float rbx = fminf(sX2[i], ox2), rby = fminf(sY2[i], oy2);
            float iw = fmaxf(rbx - ltx, 0.f), ih = fmaxf(rby - lty, 0.f);
            float inter = iw * ih;
            float iou = inter / (sAR[i] + area - inter + 1e-9f);
            if (iou > 0.5f) { kp = false; }
          }
        }
        if (!kp) keepL[t] = 0;
      }
    }
    __syncthreads();
  }

  bool keep = keepL[t] != 0;
  u64 bal = __ballot(keep);
  int wpre = __popcll(bal & ((1ull << lane) - 1ull));
  if (lane == 0) wsum[wid] = __popcll(bal);
  __syncthreads();
  int offn = 0, KT = 0;
  for (int q = 0; q < 16; q++) {
    int v = wsum[q];
    if (q < wid) offn += v;
    KT += v;
  }
  int rank = offn + wpre;
  float* outB = out;
  float* outS = out + 1600;
  float* outL = out + 2000;
  if (keep && rank < 100) {
    size_t s = (size_t)b*100 + rank;
    outB[s*4+0] = cb0; outB[s*4+1] = cb1;
    outB[s*4+2] = cb2; outB[s*4+3] = cb3;
    outS[s] = score; outL[s] = (float)label;
  }
  if (t < 100 && t >= KT) {
    size_t s = (size_t)b*100 + t;
    outB[s*4+0] = 0.f; outB[s*4+1] = 0.f; outB[s*4+2] = 0.f; outB[s*4+3] = 0.f;
    outS[s] = 0.f; outL[s] = 0.f;
  }
}

extern "C" void kernel_launch(void* const* d_in, const int* in_sizes, int n_in,
                              void* d_out, int out_size, void* d_ws, size_t ws_size,
                              hipStream_t stream) {
  (void)in_sizes; (void)n_in; (void)out_size; (void)ws_size;
  const float* feat  = (const float*)d_in[0];
  const float* props = (const float*)d_in[1];
  const float* W6 = (const float*)d_in[2];
  const float* b6 = (const float*)d_in[3];
  const float* W7 = (const float*)d_in[4];
  const float* b7 = (const float*)d_in[5];
  const float* Wc = (const float*)d_in[6];
  const float* bc = (const float*)d_in[7];
  const float* Wb = (const float*)d_in[8];
  const float* bb = (const float*)d_in[9];
  float* out = (float*)d_out;
  char* ws = (char*)d_ws;

  // workspace (peak 113,639,424 B == proven budget):
  //   phase A: featT [0, 62.26MB) + Xs2 [62.26MB, 113.64MB)
  //   phase B (featT dead): part [0, 32MB) + everything else in [32MB, 50MB)
  float* featT  = (float*)(ws);                        // 62,259,200 B
  u16*   Xs2    = (u16*)  (ws + 62259200);             // 51,380,224 B (tiled)
  float* part   = (float*)(ws);                        // 33,554,432 B (8 slices)
  u16*   Y1s2   = (u16*)  (ws + 33554432);             //  4,194,304 B (tiled)
  u16*   Y2s2   = (u16*)  (ws + 37748736);             //  4,194,304 B (tiled)
  float* Wcat   = (float*)(ws + 41943040);             //  2,097,152 B
  float* bcat   = (float*)(ws + 44040192);             //      2,048 B
  float* logitsP= (float*)(ws + 44564480);             //    372,736 B
  float* deltasP= (float*)(ws + 45088768);             //  1,490,944 B
  float* cboxes = (float*)(ws + 46661632);             //  1,474,560 B
  u64*   keys   = (u64*)  (ws + 48234496);             //    737,280 B
  u64*   sorted = (u64*)  (ws + 49020928);             //     65,536 B

  dim3 gT(475, 8, 4);
  k_transpose<<<gT, 256, 0, stream>>>(feat, featT);
  k_roialign<<<1024, 256, 0, stream>>>(featT, props, Xs2);
  k_packW<<<2048, 256, 0, stream>>>(Wc, Wb, bc, bb, Wcat, bcat);

  // FC6: K=12544 (kg=1568), split-K=8, 49 steps/slice, 512 blocks
  k_gemm_f16<<<512, 512, 0, stream>>>(Xs2, W6, part, DIN/8, 49, 8, 1024, 1048576);
  k_reduce_split<<<512, 256, 0, stream>>>(part, b6, Y1s2);
  // FC7: K=1024 (kg=128), split-K=8, 4 steps/slice
  k_gemm_f16<<<512, 512, 0, stream>>>(Y1s2, W7, part, 128, 4, 8, 1024, 1048576);
  k_reduce_split<<<512, 256, 0, stream>>>(part, b7, Y2s2);
  // heads: M=1024, N=512(padded 455), K=1024, split-K=8, 256 blocks, nct=4
  k_gemm_f16<<<256, 512, 0, stream>>>(Y2s2, Wcat, part, 128, 4, 4, 512, 524288);
  k_reduce_heads<<<2048, 256, 0, stream>>>(part, bcat, logitsP, deltasP);

  k_decode<<<1024, 128, 0, stream>>>(logitsP, deltasP, props, cboxes, keys);
  k_sort<<<8, 1024, 0, stream>>>(keys, sorted);
  k_nms<<<4, 1024, 0, stream>>>(sorted, cboxes, out);
}

// Round 11
// 349.949 us; speedup vs baseline: 1.0427x; 1.0427x over previous
//
#include <hip/hip_runtime.h>
#include <hip/hip_bf16.h>
#include <stdint.h>

#define B_    4
#define N_    256
#define C_    256
#define FH_   100
#define FW_   152
#define P_HW  (FH_*FW_)      // 15200
#define NCLS  91
#define CAND  23040          // N_*90
#define DIN   12544
#define PRE   1024

typedef unsigned long long u64;
typedef unsigned int u32;
typedef unsigned short u16;
typedef __attribute__((ext_vector_type(8))) _Float16 half8;
typedef __attribute__((ext_vector_type(8))) short short8;
typedef __attribute__((ext_vector_type(4))) float f32x4;

__device__ inline u16 h2bits(_Float16 h) { return *reinterpret_cast<u16*>(&h); }

// split v (already prescaled) into fp16 h0 + h1, exact-residual style
__device__ inline void split2(float v, u16& b0, u16& b1) {
  _Float16 h0 = (_Float16)v;
  float r = v - (float)h0;
  _Float16 h1 = (_Float16)r;
  b0 = h2bits(h0); b1 = h2bits(h1);
}

__device__ inline void gload_lds16(const void* g, void* l) {
  __builtin_amdgcn_global_load_lds(
      (const __attribute__((address_space(1))) void*)g,
      (__attribute__((address_space(3))) void*)l, 16, 0, 0);
}

// ---------------- feature transpose (B,C,H,W) -> (B,H,W,C) ----------------
__global__ void k_transpose(const float* __restrict__ in, float* __restrict__ out) {
  __shared__ float t[32][33];
  int b  = blockIdx.z;
  int c0 = blockIdx.y * 32;
  int p0 = blockIdx.x * 32;
  int tx = threadIdx.x & 31, ty = threadIdx.x >> 5;
  const float* inb = in  + (size_t)b * C_ * P_HW;
  float*       ob  = out + (size_t)b * P_HW * C_;
  #pragma unroll
  for (int q = 0; q < 4; q++)
    t[ty + q*8][tx] = inb[(size_t)(c0 + ty + q*8) * P_HW + p0 + tx];
  __syncthreads();
  #pragma unroll
  for (int q = 0; q < 4; q++)
    ob[(size_t)(p0 + ty + q*8) * C_ + c0 + tx] = t[tx][ty + q*8];
}

// ------- roi align -> Xt [2 planes][DIN/8][1024 rows][8] fp16 of (X*16) ----
__global__ __launch_bounds__(256, 8) void k_roialign(const float* __restrict__ featT,
                                                     const float* __restrict__ props,
                                                     u16* __restrict__ Xs) {
  __shared__ float sPW[196][8];     // {p00,p01,p10,p11,w00,w01,w10,w11}
  __shared__ float cellv[32][51];   // [ch-in-group][cell]
  int bid = blockIdx.x;
  int xcd = bid & 7;
  int b = xcd >> 1;
  int n = ((bid >> 3) << 1) | (xcd & 1);
  int r = (b << 8) | n;                 // bijective 0..1023, XCD-batch affine
  int tid = threadIdx.x;

  float x1 = props[r*4+0], y1 = props[r*4+1];
  float x2 = props[r*4+2], y2 = props[r*4+3];
  float x1s = x1 * 0.125f, y1s = y1 * 0.125f;
  float x2s = x2 * 0.125f, y2s = y2 * 0.125f;
  float rw = fmaxf(x2s - x1s, 1.0f);
  float rh = fmaxf(y2s - y1s, 1.0f);
  float rwd = rw / 7.0f, rhd = rh / 7.0f;

  if (tid < 196) {
    int cell = tid >> 2, s = tid & 3;
    int py = cell / 7, px = cell % 7;
    int sy = s >> 1, sx = s & 1;
    float gqy = (float)py + 0.25f + 0.5f * (float)sy;
    float gqx = (float)px + 0.25f + 0.5f * (float)sx;
    float gy = fminf(fmaxf(y1s + rhd * gqy, 0.0f), 99.0f);
    float gx = fminf(fmaxf(x1s + rwd * gqx, 0.0f), 151.0f);
    float y0f = floorf(gy), x0f = floorf(gx);
    float ly = gy - y0f, lx = gx - x0f;
    int y0i = (int)y0f;
    int y1i = (int)fminf(y0f + 1.0f, 99.0f);
    int x0i = (int)x0f;
    int x1i = (int)fminf(x0f + 1.0f, 151.0f);
    sPW[tid][0] = __int_as_float((y0i * FW_ + x0i) * 256);
    sPW[tid][1] = __int_as_float((y0i * FW_ + x1i) * 256);
    sPW[tid][2] = __int_as_float((y1i * FW_ + x0i) * 256);
    sPW[tid][3] = __int_as_float((y1i * FW_ + x1i) * 256);
    sPW[tid][4] = (1.f-ly)*(1.f-lx);
    sPW[tid][5] = (1.f-ly)*lx;
    sPW[tid][6] = ly*(1.f-lx);
    sPW[tid][7] = ly*lx;
  }
  __syncthreads();

  int c32 = tid & 31;
  int slot = tid >> 5;
  const size_t PLS = (size_t)(DIN/8) * 1024 * 8;

  for (int g = 0; g < 8; g++) {
    const float* fb = featT + (size_t)b * P_HW * C_ + g*32 + c32;
    for (int cell = slot; cell < 49; cell += 8) {
      float acc = 0.f;
      #pragma unroll
      for (int s = 0; s < 4; s++) {
        int cs = cell*4 + s;
        float4 pv = *(const float4*)&sPW[cs][0];
        float4 wv = *(const float4*)&sPW[cs][4];
        acc += wv.x * fb[__float_as_int(pv.x)]
             + wv.y * fb[__float_as_int(pv.y)]
             + wv.z * fb[__float_as_int(pv.z)]
             + wv.w * fb[__float_as_int(pv.w)];
      }
      cellv[c32][cell] = acc * 4.0f;   // 0.25 (avg) * 16 (prescale)
    }
    __syncthreads();
    if (tid < 196) {
      short8 v0, v1;
      #pragma unroll
      for (int e = 0; e < 8; e++) {
        int kl = tid*8 + e;
        int chl = kl / 49;
        int cell = kl - chl*49;
        float v = cellv[chl][cell];
        u16 h0, h1;
        split2(v, h0, h1);
        v0[e] = (short)h0; v1[e] = (short)h1;
      }
      size_t cg = (size_t)g*196 + tid;
      size_t base = (cg * 1024 + r) * 8;
      *reinterpret_cast<short8*>(Xs + base)       = v0;
      *reinterpret_cast<short8*>(Xs + PLS + base) = v1;
    }
    __syncthreads();
  }
}

// -------- MFMA GEMM (fp32 B in-kernel split), round-8 proven config --------
// fp32 via fp16 2-plane 3-pass (a0b0+a1b0+a0b1). 128x128 tile, 8 waves,
// wave tile 64x32, double-buffered LDS (2x32KB -> 2 blocks/CU), vmcnt(4).
__global__ __launch_bounds__(512) void k_gemm_f16(
    const u16* __restrict__ As, const float* __restrict__ Bw,
    float* __restrict__ part, int kg, int nsteps, int nct, int outw,
    size_t sstride) {
  __shared__ __align__(16) char lds[65536];   // 2 x (A 16KB + B 16KB)
  int tid = threadIdx.x;
  int wid = tid >> 6, lane = tid & 63;
  int l15 = lane & 15, lq = lane >> 4;
  int bid = blockIdx.x;
  int z = bid & 7, xy = bid >> 3;              // one K-slice per XCD
  int col0 = (xy % nct) * 128, row0 = (xy / nct) * 128;
  int wr = wid >> 2, wc = wid & 3;             // 8 waves: 2 row x 4 col, 64x32
  int kbase0 = z * nsteps * 32;

  auto STAGE = [&](int s, int bsel) {
    int kb = kbase0 + s * 32;
    char* dst = lds + bsel * 32768;
    #pragma unroll
    for (int j = 0; j < 4; j++) {
      int cid = tid + j*512;
      const char* src;
      if (j < 2) {
        int pl = cid >> 9;
        int kc = (cid >> 7) & 3, rr = cid & 127;
        src = (const char*)(As + ((size_t)(pl*kg + (kb>>3) + kc)*1024 + row0 + rr)*8);
      } else {
        int cid2 = cid - 1024;
        int kk = cid2 >> 5, c4 = cid2 & 31;
        int col = (c4*4) ^ (((kk >> 3) & 1) << 4);
        src = (const char*)(Bw + (size_t)(kb + kk)*outw + col0 + col);
      }
      gload_lds16(src, dst + (size_t)cid*16);
    }
  };

  f32x4 acc[4][2];
  #pragma unroll
  for (int i = 0; i < 4; i++)
    #pragma unroll
    for (int j = 0; j < 2; j++)
      #pragma unroll
      for (int q = 0; q < 4; q++) acc[i][j][q] = 0.f;

  STAGE(0, 0);
  for (int s = 0; s < nsteps; s++) {
    int cur = s & 1;
    if (s + 1 < nsteps) {
      STAGE(s + 1, cur ^ 1);
      asm volatile("s_waitcnt vmcnt(4)" ::: "memory");   // cur buf complete
    } else {
      asm volatile("s_waitcnt vmcnt(0)" ::: "memory");
    }
    __builtin_amdgcn_s_barrier();
    __builtin_amdgcn_sched_barrier(0);   // no LDS reads above the barrier

    const u16*   Alds = (const u16*)(lds + cur * 32768);
    const float* Blds = (const float*)(lds + cur * 32768 + 16384);

    half8 af[2][4];
    #pragma unroll
    for (int pl = 0; pl < 2; pl++)
      #pragma unroll
      for (int fr = 0; fr < 4; fr++) {
        int chunk = (pl*4 + lq)*128 + wr*64 + fr*16 + l15;
        af[pl][fr] = *reinterpret_cast<const half8*>(&Alds[(size_t)chunk*8]);
      }
    int cxor = (lq & 1) << 4;
    #pragma unroll
    for (int fc = 0; fc < 2; fc++) {
      int colx = (wc*32 + fc*16 + l15) ^ cxor;
      half8 b0, b1;
      #pragma unroll
      for (int j = 0; j < 8; j++) {
        float w = Blds[(lq*8 + j)*128 + colx] * 128.0f;
        _Float16 h0 = (_Float16)w;
        float rres = w - (float)h0;
        b0[j] = h0; b1[j] = (_Float16)rres;
      }
      #pragma unroll
      for (int fr = 0; fr < 4; fr++) {
        acc[fr][fc] = __builtin_amdgcn_mfma_f32_16x16x32_f16(af[0][fr], b0, acc[fr][fc], 0, 0, 0);
        acc[fr][fc] = __builtin_amdgcn_mfma_f32_16x16x32_f16(af[1][fr], b0, acc[fr][fc], 0, 0, 0);
        acc[fr][fc] = __builtin_amdgcn_mfma_f32_16x16x32_f16(af[0][fr], b1, acc[fr][fc], 0, 0, 0);
      }
    }
    // all LDS reads of cur buf must complete before next STAGE overwrites it
    __builtin_amdgcn_sched_barrier(0);
    asm volatile("s_waitcnt lgkmcnt(0)" ::: "memory");
    __builtin_amdgcn_s_barrier();
  }

  float* pp = part + (size_t)z * sstride;
  #pragma unroll
  for (int fr = 0; fr < 4; fr++)
    #pragma unroll
    for (int fc = 0; fc < 2; fc++) {
      int col = col0 + wc*32 + fc*16 + l15;
      #pragma unroll
      for (int rr = 0; rr < 4; rr++) {
        int row = row0 + wr*64 + fr*16 + lq*4 + rr;
        pp[(size_t)row*outw + col] = acc[fr][fc][rr];
      }
    }
}

// -------- MFMA GEMM, pre-split fp16 2-plane B (FC7 / heads) ---------------
// B pre-tiled in global as [pl][K/8][outw][8] fp16 of (B*128): staging is
// linear gload_lds16 (like A) and B fragments are direct ds_read_b128 —
// no strided b32 reads, no in-kernel split VALU. Same MFMA order as the
// fp32-B path -> bit-identical results.
__global__ __launch_bounds__(512) void k_gemm_f16b(
    const u16* __restrict__ As, const u16* __restrict__ Bt,
    float* __restrict__ part, int kgA, int kgB, int nsteps, int nct, int outw,
    size_t sstride) {
  __shared__ __align__(16) char lds[65536];   // 2 x (A 16KB + B 16KB)
  int tid = threadIdx.x;
  int wid = tid >> 6, lane = tid & 63;
  int l15 = lane & 15, lq = lane >> 4;
  int bid = blockIdx.x;
  int z = bid & 7, xy = bid >> 3;
  int col0 = (xy % nct) * 128, row0 = (xy / nct) * 128;
  int wr = wid >> 2, wc = wid & 3;             // 8 waves: 2 row x 4 col, 64x32
  int kbase0 = z * nsteps * 32;

  auto STAGE = [&](int s, int bsel) {
    int kb = kbase0 + s * 32;
    char* dst = lds + bsel * 32768;
    #pragma unroll
    for (int j = 0; j < 4; j++) {
      int cid = tid + j*512;
      const char* src;
      if (j < 2) {
        int pl = cid >> 9;
        int kc = (cid >> 7) & 3, rr = cid & 127;
        src = (const char*)(As + ((size_t)(pl*kgA + (kb>>3) + kc)*1024 + row0 + rr)*8);
      } else {
        int cid2 = cid - 1024;
        int pl = cid2 >> 9;
        int kc = (cid2 >> 7) & 3, cc = cid2 & 127;
        src = (const char*)(Bt + ((size_t)(pl*kgB + (kb>>3) + kc)*outw + col0 + cc)*8);
      }
      gload_lds16(src, dst + (size_t)cid*16);
    }
  };

  f32x4 acc[4][2];
  #pragma unroll
  for (int i = 0; i < 4; i++)
    #pragma unroll
    for (int j = 0; j < 2; j++)
      #pragma unroll
      for (int q = 0; q < 4; q++) acc[i][j][q] = 0.f;

  STAGE(0, 0);
  for (int s = 0; s < nsteps; s++) {
    int cur = s & 1;
    if (s + 1 < nsteps) {
      STAGE(s + 1, cur ^ 1);
      asm volatile("s_waitcnt vmcnt(4)" ::: "memory");
    } else {
      asm volatile("s_waitcnt vmcnt(0)" ::: "memory");
    }
    __builtin_amdgcn_s_barrier();
    __builtin_amdgcn_sched_barrier(0);

    const u16* Alds = (const u16*)(lds + cur * 32768);
    const u16* Blds = (const u16*)(lds + cur * 32768 + 16384);

    half8 af[2][4];
    #pragma unroll
    for (int pl = 0; pl < 2; pl++)
      #pragma unroll
      for (int fr = 0; fr < 4; fr++) {
        int chunk = (pl*4 + lq)*128 + wr*64 + fr*16 + l15;
        af[pl][fr] = *reinterpret_cast<const half8*>(&Alds[(size_t)chunk*8]);
      }
    #pragma unroll
    for (int fc = 0; fc < 2; fc++) {
      int cc = wc*32 + fc*16 + l15;
      half8 b0 = *reinterpret_cast<const half8*>(&Blds[(size_t)((0*4 + lq)*128 + cc)*8]);
      half8 b1 = *reinterpret_cast<const half8*>(&Blds[(size_t)((1*4 + lq)*128 + cc)*8]);
      #pragma unroll
      for (int fr = 0; fr < 4; fr++) {
        acc[fr][fc] = __builtin_amdgcn_mfma_f32_16x16x32_f16(af[0][fr], b0, acc[fr][fc], 0, 0, 0);
        acc[fr][fc] = __builtin_amdgcn_mfma_f32_16x16x32_f16(af[1][fr], b0, acc[fr][fc], 0, 0, 0);
        acc[fr][fc] = __builtin_amdgcn_mfma_f32_16x16x32_f16(af[0][fr], b1, acc[fr][fc], 0, 0, 0);
      }
    }
    __builtin_amdgcn_sched_barrier(0);
    asm volatile("s_waitcnt lgkmcnt(0)" ::: "memory");
    __builtin_amdgcn_s_barrier();
  }

  float* pp = part + (size_t)z * sstride;
  #pragma unroll
  for (int fr = 0; fr < 4; fr++)
    #pragma unroll
    for (int fc = 0; fc < 2; fc++) {
      int col = col0 + wc*32 + fc*16 + l15;
      #pragma unroll
      for (int rr = 0; rr < 4; rr++) {
        int row = row0 + wr*64 + fr*16 + lq*4 + rr;
        pp[(size_t)row*outw + col] = acc[fr][fc][rr];
      }
    }
}

// -------- pack W7 -> tiled fp16 2-plane [pl][128][1024][8] of (W7*128) ----
__global__ void k_packW7(const float* __restrict__ W7, u16* __restrict__ Bt) {
  int idx = blockIdx.x * 256 + threadIdx.x;   // 131072 = 128 ko x 1024 col
  int col = idx & 1023, ko = idx >> 10;
  short8 c0, c1;
  #pragma unroll
  for (int e = 0; e < 8; e++) {
    float w = W7[(size_t)(ko*8 + e)*1024 + col] * 128.0f;
    u16 h0, h1;
    split2(w, h0, h1);
    c0[e] = (short)h0; c1[e] = (short)h1;
  }
  *reinterpret_cast<short8*>(Bt + ((size_t)ko*1024 + col)*8)         = c0;
  *reinterpret_cast<short8*>(Bt + ((size_t)(128 + ko)*1024 + col)*8) = c1;
}

// -------- pack heads Wc|Wb -> tiled fp16 2-plane [pl][128][512][8], bcat ---
__global__ void k_packHeads(const float* __restrict__ Wc, const float* __restrict__ Wb,
                            const float* __restrict__ bc, const float* __restrict__ bb,
                            u16* __restrict__ Bt, float* __restrict__ bcat) {
  int idx = blockIdx.x * 256 + threadIdx.x;   // 65536 = 128 ko x 512 col
  int col = idx & 511, ko = idx >> 9;
  short8 c0, c1;
  #pragma unroll
  for (int e = 0; e < 8; e++) {
    int k = ko*8 + e;
    float w = 0.f;
    if (col < 91)       w = Wc[(size_t)k*91 + col];
    else if (col < 455) w = Wb[(size_t)k*364 + (col - 91)];
    w *= 128.0f;
    u16 h0, h1;
    split2(w, h0, h1);
    c0[e] = (short)h0; c1[e] = (short)h1;
  }
  *reinterpret_cast<short8*>(Bt + ((size_t)ko*512 + col)*8)         = c0;
  *reinterpret_cast<short8*>(Bt + ((size_t)(128 + ko)*512 + col)*8) = c1;
  if (idx < 512) {
    float bv = 0.f;
    if (idx < 91)       bv = bc[idx];
    else if (idx < 455) bv = bb[idx - 91];
    bcat[idx] = bv;
  }
}

// -------- reduce split-K -> tiled fp16 planes (coalesced reads) ------------
__global__ void k_reduce_split(const float* __restrict__ part,
                               const float* __restrict__ bias,
                               u16* __restrict__ ys) {
  int idx = blockIdx.x * 256 + threadIdx.x;   // 131072 = 1024 rows * 128 cg
  int row = idx >> 7, cg = idx & 127;
  float4 s0 = {0,0,0,0}, s1 = {0,0,0,0};
  #pragma unroll
  for (int s = 0; s < 8; s++) {
    const float4* p = (const float4*)(part + (size_t)s*1048576 + (size_t)row*1024 + cg*8);
    float4 a = p[0], b = p[1];
    s0.x += a.x; s0.y += a.y; s0.z += a.z; s0.w += a.w;
    s1.x += b.x; s1.y += b.y; s1.z += b.z; s1.w += b.w;
  }
  float v[8] = {s0.x, s0.y, s0.z, s0.w, s1.x, s1.y, s1.z, s1.w};
  short8 o0, o1;
  #pragma unroll
  for (int e = 0; e < 8; e++) {
    float x = v[e] * (1.0f/2048.0f) + bias[cg*8 + e];
    x = fmaxf(x, 0.f) * 16.0f;                // prescale for next layer
    u16 h0, h1;
    split2(x, h0, h1);
    o0[e] = (short)h0; o1[e] = (short)h1;
  }
  size_t base = ((size_t)cg * 1024 + row) * 8;   // kg = 128 for K=1024
  *reinterpret_cast<short8*>(ys + base)               = o0;
  *reinterpret_cast<short8*>(ys + (size_t)1048576 + base) = o1;
}

// -------- heads reduce: sum 8 slices, +bcat, scatter to logits/deltas ------
__global__ void k_reduce_heads(const float* __restrict__ part,
                               const float* __restrict__ bcat,
                               float* __restrict__ logits,
                               float* __restrict__ deltas) {
  int idx = blockIdx.x * 256 + threadIdx.x;   // 524288 = 1024 * 512
  int row = idx >> 9, col = idx & 511;
  float v = 0.f;
  #pragma unroll
  for (int s = 0; s < 8; s++) v += part[idx + (size_t)s*524288];
  v = v * (1.0f/2048.0f) + bcat[col];
  if (col < 91)       logits[(size_t)row*91 + col] = v;
  else if (col < 455) deltas[(size_t)row*364 + (col - 91)] = v;
}

// -------- softmax + box decode + candidate keys ----------------------------
__global__ void k_decode(const float* __restrict__ logits,
                         const float* __restrict__ deltas,
                         const float* __restrict__ props,
                         float* __restrict__ cboxes,
                         u64* __restrict__ keys) {
  int r = blockIdx.x;
  int j = threadIdx.x;   // 128
  __shared__ float red[128];
  float lg = (j < NCLS) ? logits[r*NCLS + j] : -3.4e38f;
  red[j] = lg;
  __syncthreads();
  for (int s = 64; s > 0; s >>= 1) {
    if (j < s) red[j] = fmaxf(red[j], red[j+s]);
    __syncthreads();
  }
  float mx = red[0];
  __syncthreads();
  float e = (j < NCLS) ? expf(lg - mx) : 0.f;
  red[j] = e;
  __syncthreads();
  for (int s = 64; s > 0; s >>= 1) {
    if (j < s) red[j] += red[j+s];
    __syncthreads();
  }
  float p = e / red[0];
  if (j >= 1 && j < NCLS) {
    float px1 = props[r*4+0], py1 = props[r*4+1];
    float px2 = props[r*4+2], py2 = props[r*4+3];
    float w = px2 - px1, h = py2 - py1;
    float cx = px1 + 0.5f*w, cy = py1 + 0.5f*h;
    float d0 = deltas[r*364 + j*4 + 0];
    float d1 = deltas[r*364 + j*4 + 1];
    float d2 = deltas[r*364 + j*4 + 2];
    float d3 = deltas[r*364 + j*4 + 3];
    float dx = d0 / 10.0f, dy = d1 / 10.0f;
    float dw = fminf(d2 / 5.0f, 4.135166556742356f);
    float dh = fminf(d3 / 5.0f, 4.135166556742356f);
    float pcx = dx*w + cx, pcy = dy*h + cy;
    float pw = expf(dw)*w, ph = expf(dh)*h;
    float bx1 = fminf(fmaxf(pcx - 0.5f*pw, 0.f), 1216.f);
    float by1 = fminf(fmaxf(pcy - 0.5f*ph, 0.f),  800.f);
    float bx2 = fminf(fmaxf(pcx + 0.5f*pw, 0.f), 1216.f);
    float by2 = fminf(fmaxf(pcy + 0.5f*ph, 0.f),  800.f);
    bool valid = (p > 0.05f) && ((bx2 - bx1) >= 0.01f) && ((by2 - by1) >= 0.01f);
    int b = r >> 8, n = r & 255;
    int cidx = n*90 + (j-1);
    size_t cb = (size_t)b*CAND + cidx;
    cboxes[cb*4+0] = bx1; cboxes[cb*4+1] = by1;
    cboxes[cb*4+2] = bx2; cboxes[cb*4+3] = by2;
    u64 key = 0ull;
    if (valid)
      key = (((u64)__float_as_uint(p)) << 32) | (u32)(~(u32)cidx);
    keys[cb] = key;
  }
}

// -------- per (batch,half): compact valid + bitonic sort desc, top1024 -----
#define SORTN 4096
__global__ __launch_bounds__(1024) void k_sort(const u64* __restrict__ keys,
                                               u64* __restrict__ sorted) {
  __shared__ u64 sk[SORTN];
  __shared__ int cnt;
  int t = threadIdx.x;
  int b = blockIdx.x >> 1, h = blockIdx.x & 1;
  if (t == 0) cnt = 0;
  __syncthreads();
  const u64* kb = keys + (size_t)b*CAND + (size_t)h*(CAND/2);
  for (int q = 0; q < 12; q++) {
    int idx = t + q*1024;
    if (idx < CAND/2) {
      u64 k = kb[idx];
      if (k) { int pos = atomicAdd(&cnt, 1); sk[pos] = k; }
    }
  }
  __syncthreads();
  int total = cnt;
  for (int s = t; s < SORTN; s += 1024)
    if (s >= total) sk[s] = 0ull;
  __syncthreads();
  for (int k = 2; k <= SORTN; k <<= 1) {
    for (int jj = k >> 1; jj > 0; jj >>= 1) {
      for (int i = t; i < SORTN; i += 1024) {
        int ixj = i ^ jj;
        if (ixj > i) {
          u64 a = sk[i], bb = sk[ixj];
          bool up = ((i & k) == 0);
          if (up ? (a < bb) : (a > bb)) { sk[i] = bb; sk[ixj] = a; }
        }
      }
      __syncthreads();
    }
  }
  sorted[((size_t)b*2 + h)*1024 + t] = sk[t];
}

// -------- per batch: merge halves, tiled greedy NMS, emit final 100 --------
__global__ __launch_bounds__(1024) void k_nms(const u64* __restrict__ sorted,
                                              const float* __restrict__ cboxes,
                                              float* __restrict__ out) {
  __shared__ u64 m[2048];
  __shared__ float sX1[1024], sY1[1024], sX2[1024], sY2[1024], sAR[1024];
  __shared__ int keepL[1024];
  __shared__ int wsum[16];
  int t = threadIdx.x;
  int b = blockIdx.x;
  m[t]        = sorted[((size_t)b*2 + 0)*1024 + t];
  m[2047 - t] = sorted[((size_t)b*2 + 1)*1024 + t];
  __syncthreads();
  for (int lg = 10; lg >= 0; lg--) {
    int jj = 1 << lg;
    int pos = ((t >> lg) << (lg+1)) + (t & (jj-1));
    u64 a = m[pos], bb = m[pos + jj];
    if (a < bb) { m[pos] = bb; m[pos + jj] = a; }
    __syncthreads();
  }
  u64 key = m[t];
  bool valid = key != 0ull;
  float score = __uint_as_float((u32)(key >> 32));
  u32 cidx = ~((u32)(key & 0xFFFFFFFFu));
  int label = valid ? (int)(cidx % 90u) + 1 : 0;
  float cb0 = 0.f, cb1 = 0.f, cb2 = 0.f, cb3 = 0.f;
  if (valid) {
    size_t cb = ((size_t)b*CAND + cidx) * 4;
    cb0 = cboxes[cb+0]; cb1 = cboxes[cb+1];
    cb2 = cboxes[cb+2]; cb3 = cboxes[cb+3];
  }
  float off = (float)label * 1218.0f;
  float ox1 = cb0 + off, oy1 = cb1 + off;
  float ox2 = cb2 + off, oy2 = cb3 + off;
  float area = (ox2 - ox1) * (oy2 - oy1);
  sX1[t] = ox1; sY1[t] = oy1; sX2[t] = ox2; sY2[t] = oy2; sAR[t] = area;
  keepL[t] = valid ? 1 : 0;
  __syncthreads();

  int wid = t >> 6, lane = t & 63;
  for (int tile = 0; tile < 16; tile++) {
    if (wid == 0) {
      int idx = tile*64 + lane;
      bool kp = keepL[idx] != 0;
      float bx1 = sX1[idx], by1 = sY1[idx], bx2 = sX2[idx], by2 = sY2[idx], ba = sAR[idx];
      u64 alive = __ballot(kp);
      #pragma unroll 1
      for (int i = 0; i < 63; i++) {
        if ((alive >> i) & 1ull) {
          int ii = tile*64 + i;
          float ltx = fmaxf(sX1[ii], bx1), lty = fmaxf(sY1[ii], by1);
          float rbx = fminf(sX2[ii], bx2), rby = fminf(sY2[ii], by2);
          float iw = fmaxf(rbx - ltx, 0.f), ih = fmaxf(rby - lty, 0.f);
          float inter = iw * ih;
          float iou = inter / (sAR[ii] + ba - inter + 1e-9f);
          if (lane > i && iou > 0.5f) kp = false;
        }
        alive = __ballot(kp);
      }
      keepL[idx] = kp ? 1 : 0;
    }
    __syncthreads();
    if (t >= (tile+1)*64) {
      bool kp = keepL[t] != 0;
      if (kp) {
        #pragma unroll 1
        for (int i = tile*64; i < tile*64 + 64; i++) {
          if (keepL[i]) {
            float ltx = fmaxf(sX1[i], ox1), lty = fmaxf(sY1[i], oy1);
            float rbx = fminf(sX2[i], ox2), rby = fminf(sY2[i], oy2);
            float iw = fmaxf(rbx - ltx, 0.f), ih = fmaxf(rby - lty, 0.f);
            float inter = iw * ih;
            float iou = inter / (sAR[i] + area - inter + 1e-9f);
            if (iou > 0.5f) { kp = false; }
          }
        }
        if (!kp) keepL[t] = 0;
      }
    }
    __syncthreads();
  }

  bool keep = keepL[t] != 0;
  u64 bal = __ballot(keep);
  int wpre = __popcll(bal & ((1ull << lane) - 1ull));
  if (lane == 0) wsum[wid] = __popcll(bal);
  __syncthreads();
  int offn = 0, KT = 0;
  for (int q = 0; q < 16; q++) {
    int v = wsum[q];
    if (q < wid) offn += v;
    KT += v;
  }
  int rank = offn + wpre;
  float* outB = out;
  float* outS = out + 1600;
  float* outL = out + 2000;
  if (keep && rank < 100) {
    size_t s = (size_t)b*100 + rank;
    outB[s*4+0] = cb0; outB[s*4+1] = cb1;
    outB[s*4+2] = cb2; outB[s*4+3] = cb3;
    outS[s] = score; outL[s] = (float)label;
  }
  if (t < 100 && t >= KT) {
    size_t s = (size_t)b*100 + t;
    outB[s*4+0] = 0.f; outB[s*4+1] = 0.f; outB[s*4+2] = 0.f; outB[s*4+3] = 0.f;
    outS[s] = 0.f; outL[s] = 0.f;
  }
}

extern "C" void kernel_launch(void* const* d_in, const int* in_sizes, int n_in,
                              void* d_out, int out_size, void* d_ws, size_t ws_size,
                              hipStream_t stream) {
  (void)in_sizes; (void)n_in; (void)out_size; (void)ws_size;
  const float* feat  = (const float*)d_in[0];
  const float* props = (const float*)d_in[1];
  const float* W6 = (const float*)d_in[2];
  const float* b6 = (const float*)d_in[3];
  const float* W7 = (const float*)d_in[4];
  const float* b7 = (const float*)d_in[5];
  const float* Wc = (const float*)d_in[6];
  const float* bc = (const float*)d_in[7];
  const float* Wb = (const float*)d_in[8];
  const float* bb = (const float*)d_in[9];
  float* out = (float*)d_out;
  char* ws = (char*)d_ws;

  // workspace (peak 113,639,424 B == proven budget):
  //   phase A: featT [0, 62.26MB) + Xs2 [62.26MB, 113.64MB)
  //   phase B (featT dead): part [0, 32MB) + everything else in [32MB, 53MB)
  float* featT  = (float*)(ws);                        // 62,259,200 B
  u16*   Xs2    = (u16*)  (ws + 62259200);             // 51,380,224 B (tiled)
  float* part   = (float*)(ws);                        // 33,554,432 B (8 slices)
  u16*   Y1s2   = (u16*)  (ws + 33554432);             //  4,194,304 B (tiled)
  u16*   Y2s2   = (u16*)  (ws + 37748736);             //  4,194,304 B (tiled)
  u16*   W7t    = (u16*)  (ws + 41943040);             //  4,194,304 B (tiled B)
  u16*   Wcatt  = (u16*)  (ws + 46137344);             //  2,097,152 B (tiled B)
  float* bcat   = (float*)(ws + 48234496);             //      2,048 B
  float* logitsP= (float*)(ws + 48238592);             //    372,736 B
  float* deltasP= (float*)(ws + 48611328);             //  1,490,944 B
  float* cboxes = (float*)(ws + 50102272);             //  1,474,560 B
  u64*   keys   = (u64*)  (ws + 51576832);             //    737,280 B
  u64*   sorted = (u64*)  (ws + 52314112);             //     65,536 B

  dim3 gT(475, 8, 4);
  k_transpose<<<gT, 256, 0, stream>>>(feat, featT);
  k_roialign<<<1024, 256, 0, stream>>>(featT, props, Xs2);
  // packs run after roialign (their outputs live in the dead featT region)
  k_packW7<<<512, 256, 0, stream>>>(W7, W7t);
  k_packHeads<<<256, 256, 0, stream>>>(Wc, Wb, bc, bb, Wcatt, bcat);

  // FC6: K=12544 (kg=1568), split-K=8, 49 steps/slice, 512 blocks (2/CU)
  k_gemm_f16<<<512, 512, 0, stream>>>(Xs2, W6, part, DIN/8, 49, 8, 1024, 1048576);
  k_reduce_split<<<512, 256, 0, stream>>>(part, b6, Y1s2);
  // FC7: K=1024, split-K=8, 4 steps/slice, fp16-B path
  k_gemm_f16b<<<512, 512, 0, stream>>>(Y1s2, W7t, part, 128, 128, 4, 8, 1024, 1048576);
  k_reduce_split<<<512, 256, 0, stream>>>(part, b7, Y2s2);
  // heads: M=1024, N=512(padded 455), K=1024, split-K=8, fp16-B path
  k_gemm_f16b<<<256, 512, 0, stream>>>(Y2s2, Wcatt, part, 128, 128, 4, 4, 512, 524288);
  k_reduce_heads<<<2048, 256, 0, stream>>>(part, bcat, logitsP, deltasP);

  k_decode<<<1024, 128, 0, stream>>>(logitsP, deltasP, props, cboxes, keys);
  k_sort<<<8, 1024, 0, stream>>>(keys, sorted);
  k_nms<<<4, 1024, 0, stream>>>(sorted, cboxes, out);
}

// Round 13
// 343.578 us; speedup vs baseline: 1.0621x; 1.0185x over previous
//
#include <hip/hip_runtime.h>
#include <hip/hip_bf16.h>
#include <stdint.h>

#define B_    4
#define N_    256
#define C_    256
#define FH_   100
#define FW_   152
#define P_HW  (FH_*FW_)      // 15200
#define NCLS  91
#define CAND  23040          // N_*90
#define DIN   12544
#define PRE   1024

typedef unsigned long long u64;
typedef unsigned int u32;
typedef unsigned short u16;
typedef __attribute__((ext_vector_type(8))) _Float16 half8;
typedef __attribute__((ext_vector_type(8))) short short8;
typedef __attribute__((ext_vector_type(4))) float f32x4;

__device__ inline u16 h2bits(_Float16 h) { return *reinterpret_cast<u16*>(&h); }

__device__ inline void split2(float v, u16& b0, u16& b1) {
  _Float16 h0 = (_Float16)v;
  float r = v - (float)h0;
  _Float16 h1 = (_Float16)r;
  b0 = h2bits(h0); b1 = h2bits(h1);
}

__device__ inline void gload_lds16(const void* g, void* l) {
  __builtin_amdgcn_global_load_lds(
      (const __attribute__((address_space(1))) void*)g,
      (__attribute__((address_space(3))) void*)l, 16, 0, 0);
}

// ---------------- feature transpose (B,C,H,W) -> (B,H,W,C) ----------------
__global__ void k_transpose(const float* __restrict__ in, float* __restrict__ out) {
  __shared__ float t[32][33];
  int b  = blockIdx.z;
  int c0 = blockIdx.y * 32;
  int p0 = blockIdx.x * 32;
  int tx = threadIdx.x & 31, ty = threadIdx.x >> 5;
  const float* inb = in  + (size_t)b * C_ * P_HW;
  float*       ob  = out + (size_t)b * P_HW * C_;
  #pragma unroll
  for (int q = 0; q < 4; q++)
    t[ty + q*8][tx] = inb[(size_t)(c0 + ty + q*8) * P_HW + p0 + tx];
  __syncthreads();
  #pragma unroll
  for (int q = 0; q < 4; q++)
    ob[(size_t)(p0 + ty + q*8) * C_ + c0 + tx] = t[tx][ty + q*8];
}

// -------- packs: W7 (blocks 0..511) + heads Wc|Wb (512..767) ---------------
__global__ void k_packs(const float* __restrict__ W7, u16* __restrict__ W7t,
                        const float* __restrict__ Wc, const float* __restrict__ Wb,
                        const float* __restrict__ bc, const float* __restrict__ bb,
                        u16* __restrict__ Wcatt, float* __restrict__ bcat) {
  int bid = blockIdx.x;
  int tid = threadIdx.x;
  if (bid < 512) {
    int idx = bid * 256 + tid;                 // 131072 = 128 ko x 1024 col
    int col = idx & 1023, ko = idx >> 10;
    short8 c0v, c1v;
    #pragma unroll
    for (int e = 0; e < 8; e++) {
      float w = W7[(size_t)(ko*8 + e)*1024 + col] * 128.0f;
      u16 h0, h1;
      split2(w, h0, h1);
      c0v[e] = (short)h0; c1v[e] = (short)h1;
    }
    *reinterpret_cast<short8*>(W7t + ((size_t)ko*1024 + col)*8)         = c0v;
    *reinterpret_cast<short8*>(W7t + ((size_t)(128 + ko)*1024 + col)*8) = c1v;
  } else {
    int idx = (bid - 512) * 256 + tid;         // 65536 = 128 ko x 512 col
    int col = idx & 511, ko = idx >> 9;
    short8 c0v, c1v;
    #pragma unroll
    for (int e = 0; e < 8; e++) {
      int k = ko*8 + e;
      float w = 0.f;
      if (col < 91)       w = Wc[(size_t)k*91 + col];
      else if (col < 455) w = Wb[(size_t)k*364 + (col - 91)];
      w *= 128.0f;
      u16 h0, h1;
      split2(w, h0, h1);
      c0v[e] = (short)h0; c1v[e] = (short)h1;
    }
    *reinterpret_cast<short8*>(Wcatt + ((size_t)ko*512 + col)*8)         = c0v;
    *reinterpret_cast<short8*>(Wcatt + ((size_t)(128 + ko)*512 + col)*8) = c1v;
    if (idx < 512) {
      float bv = 0.f;
      if (idx < 91)       bv = bc[idx];
      else if (idx < 455) bv = bb[idx - 91];
      bcat[idx] = bv;
    }
  }
}

// ------- roi align -> Xt [2 planes][DIN/8][1024 rows][8] fp16 of (X*16) ----
// PROVEN round-8..11 version: per-(cell,sample) geometry precomputed into
// LDS (196 entries), 16 gather loads per cell, channels in 8 groups of 32.
__global__ __launch_bounds__(256, 8) void k_roialign(const float* __restrict__ featT,
                                                     const float* __restrict__ props,
                                                     u16* __restrict__ Xs) {
  __shared__ float sPW[196][8];     // {p00,p01,p10,p11,w00,w01,w10,w11}
  __shared__ float cellv[32][51];   // [ch-in-group][cell]
  int bid = blockIdx.x;
  int xcd = bid & 7;
  int b = xcd >> 1;
  int n = ((bid >> 3) << 1) | (xcd & 1);
  int r = (b << 8) | n;                 // bijective 0..1023, XCD-batch affine
  int tid = threadIdx.x;

  float x1 = props[r*4+0], y1 = props[r*4+1];
  float x2 = props[r*4+2], y2 = props[r*4+3];
  float x1s = x1 * 0.125f, y1s = y1 * 0.125f;
  float x2s = x2 * 0.125f, y2s = y2 * 0.125f;
  float rw = fmaxf(x2s - x1s, 1.0f);
  float rh = fmaxf(y2s - y1s, 1.0f);
  float rwd = rw / 7.0f, rhd = rh / 7.0f;

  if (tid < 196) {
    int cell = tid >> 2, s = tid & 3;
    int py = cell / 7, px = cell % 7;
    int sy = s >> 1, sx = s & 1;
    float gqy = (float)py + 0.25f + 0.5f * (float)sy;
    float gqx = (float)px + 0.25f + 0.5f * (float)sx;
    float gy = fminf(fmaxf(y1s + rhd * gqy, 0.0f), 99.0f);
    float gx = fminf(fmaxf(x1s + rwd * gqx, 0.0f), 151.0f);
    float y0f = floorf(gy), x0f = floorf(gx);
    float ly = gy - y0f, lx = gx - x0f;
    int y0i = (int)y0f;
    int y1i = (int)fminf(y0f + 1.0f, 99.0f);
    int x0i = (int)x0f;
    int x1i = (int)fminf(x0f + 1.0f, 151.0f);
    sPW[tid][0] = __int_as_float((y0i * FW_ + x0i) * 256);
    sPW[tid][1] = __int_as_float((y0i * FW_ + x1i) * 256);
    sPW[tid][2] = __int_as_float((y1i * FW_ + x0i) * 256);
    sPW[tid][3] = __int_as_float((y1i * FW_ + x1i) * 256);
    sPW[tid][4] = (1.f-ly)*(1.f-lx);
    sPW[tid][5] = (1.f-ly)*lx;
    sPW[tid][6] = ly*(1.f-lx);
    sPW[tid][7] = ly*lx;
  }
  __syncthreads();

  int c32 = tid & 31;
  int slot = tid >> 5;
  const size_t PLS = (size_t)(DIN/8) * 1024 * 8;

  for (int g = 0; g < 8; g++) {
    const float* fb = featT + (size_t)b * P_HW * C_ + g*32 + c32;
    for (int cell = slot; cell < 49; cell += 8) {
      float acc = 0.f;
      #pragma unroll
      for (int s = 0; s < 4; s++) {
        int cs = cell*4 + s;
        float4 pv = *(const float4*)&sPW[cs][0];
        float4 wv = *(const float4*)&sPW[cs][4];
        acc += wv.x * fb[__float_as_int(pv.x)]
             + wv.y * fb[__float_as_int(pv.y)]
             + wv.z * fb[__float_as_int(pv.z)]
             + wv.w * fb[__float_as_int(pv.w)];
      }
      cellv[c32][cell] = acc * 4.0f;   // 0.25 (avg) * 16 (prescale)
    }
    __syncthreads();
    if (tid < 196) {
      short8 v0, v1;
      #pragma unroll
      for (int e = 0; e < 8; e++) {
        int kl = tid*8 + e;
        int chl = kl / 49;
        int cell = kl - chl*49;
        float v = cellv[chl][cell];
        u16 h0, h1;
        split2(v, h0, h1);
        v0[e] = (short)h0; v1[e] = (short)h1;
      }
      size_t cg = (size_t)g*196 + tid;
      size_t base = (cg * 1024 + r) * 8;
      *reinterpret_cast<short8*>(Xs + base)       = v0;
      *reinterpret_cast<short8*>(Xs + PLS + base) = v1;
    }
    __syncthreads();
  }
}

// -------- MFMA GEMM (fp32 B in-kernel split), round-8 proven config --------
__global__ __launch_bounds__(512) void k_gemm_f16(
    const u16* __restrict__ As, const float* __restrict__ Bw,
    float* __restrict__ part, int kg, int nsteps, int nct, int outw,
    size_t sstride) {
  __shared__ __align__(16) char lds[65536];
  int tid = threadIdx.x;
  int wid = tid >> 6, lane = tid & 63;
  int l15 = lane & 15, lq = lane >> 4;
  int bid = blockIdx.x;
  int z = bid & 7, xy = bid >> 3;
  int col0 = (xy % nct) * 128, row0 = (xy / nct) * 128;
  int wr = wid >> 2, wc = wid & 3;
  int kbase0 = z * nsteps * 32;

  auto STAGE = [&](int s, int bsel) {
    int kb = kbase0 + s * 32;
    char* dst = lds + bsel * 32768;
    #pragma unroll
    for (int j = 0; j < 4; j++) {
      int cid = tid + j*512;
      const char* src;
      if (j < 2) {
        int pl = cid >> 9;
        int kc = (cid >> 7) & 3, rr = cid & 127;
        src = (const char*)(As + ((size_t)(pl*kg + (kb>>3) + kc)*1024 + row0 + rr)*8);
      } else {
        int cid2 = cid - 1024;
        int kk = cid2 >> 5, c4 = cid2 & 31;
        int col = (c4*4) ^ (((kk >> 3) & 1) << 4);
        src = (const char*)(Bw + (size_t)(kb + kk)*outw + col0 + col);
      }
      gload_lds16(src, dst + (size_t)cid*16);
    }
  };

  f32x4 acc[4][2];
  #pragma unroll
  for (int i = 0; i < 4; i++)
    #pragma unroll
    for (int j = 0; j < 2; j++)
      #pragma unroll
      for (int q = 0; q < 4; q++) acc[i][j][q] = 0.f;

  STAGE(0, 0);
  for (int s = 0; s < nsteps; s++) {
    int cur = s & 1;
    if (s + 1 < nsteps) {
      STAGE(s + 1, cur ^ 1);
      asm volatile("s_waitcnt vmcnt(4)" ::: "memory");
    } else {
      asm volatile("s_waitcnt vmcnt(0)" ::: "memory");
    }
    __builtin_amdgcn_s_barrier();
    __builtin_amdgcn_sched_barrier(0);

    const u16*   Alds = (const u16*)(lds + cur * 32768);
    const float* Blds = (const float*)(lds + cur * 32768 + 16384);

    half8 af[2][4];
    #pragma unroll
    for (int pl = 0; pl < 2; pl++)
      #pragma unroll
      for (int fr = 0; fr < 4; fr++) {
        int chunk = (pl*4 + lq)*128 + wr*64 + fr*16 + l15;
        af[pl][fr] = *reinterpret_cast<const half8*>(&Alds[(size_t)chunk*8]);
      }
    int cxor = (lq & 1) << 4;
    #pragma unroll
    for (int fc = 0; fc < 2; fc++) {
      int colx = (wc*32 + fc*16 + l15) ^ cxor;
      half8 b0, b1;
      #pragma unroll
      for (int j = 0; j < 8; j++) {
        float w = Blds[(lq*8 + j)*128 + colx] * 128.0f;
        _Float16 h0 = (_Float16)w;
        float rres = w - (float)h0;
        b0[j] = h0; b1[j] = (_Float16)rres;
      }
      #pragma unroll
      for (int fr = 0; fr < 4; fr++) {
        acc[fr][fc] = __builtin_amdgcn_mfma_f32_16x16x32_f16(af[0][fr], b0, acc[fr][fc], 0, 0, 0);
        acc[fr][fc] = __builtin_amdgcn_mfma_f32_16x16x32_f16(af[1][fr], b0, acc[fr][fc], 0, 0, 0);
        acc[fr][fc] = __builtin_amdgcn_mfma_f32_16x16x32_f16(af[0][fr], b1, acc[fr][fc], 0, 0, 0);
      }
    }
    __builtin_amdgcn_sched_barrier(0);
    asm volatile("s_waitcnt lgkmcnt(0)" ::: "memory");
    __builtin_amdgcn_s_barrier();
  }

  float* pp = part + (size_t)z * sstride;
  #pragma unroll
  for (int fr = 0; fr < 4; fr++)
    #pragma unroll
    for (int fc = 0; fc < 2; fc++) {
      int col = col0 + wc*32 + fc*16 + l15;
      #pragma unroll
      for (int rr = 0; rr < 4; rr++) {
        int row = row0 + wr*64 + fr*16 + lq*4 + rr;
        pp[(size_t)row*outw + col] = acc[fr][fc][rr];
      }
    }
}

// -------- MFMA GEMM, pre-split fp16 2-plane B (FC7 / heads) ---------------
__global__ __launch_bounds__(512) void k_gemm_f16b(
    const u16* __restrict__ As, const u16* __restrict__ Bt,
    float* __restrict__ part, int kgA, int kgB, int nsteps, int nct, int outw,
    size_t sstride) {
  __shared__ __align__(16) char lds[65536];
  int tid = threadIdx.x;
  int wid = tid >> 6, lane = tid & 63;
  int l15 = lane & 15, lq = lane >> 4;
  int bid = blockIdx.x;
  int z = bid & 7, xy = bid >> 3;
  int col0 = (xy % nct) * 128, row0 = (xy / nct) * 128;
  int wr = wid >> 2, wc = wid & 3;
  int kbase0 = z * nsteps * 32;

  auto STAGE = [&](int s, int bsel) {
    int kb = kbase0 + s * 32;
    char* dst = lds + bsel * 32768;
    #pragma unroll
    for (int j = 0; j < 4; j++) {
      int cid = tid + j*512;
      const char* src;
      if (j < 2) {
        int pl = cid >> 9;
        int kc = (cid >> 7) & 3, rr = cid & 127;
        src = (const char*)(As + ((size_t)(pl*kgA + (kb>>3) + kc)*1024 + row0 + rr)*8);
      } else {
        int cid2 = cid - 1024;
        int pl = cid2 >> 9;
        int kc = (cid2 >> 7) & 3, cc = cid2 & 127;
        src = (const char*)(Bt + ((size_t)(pl*kgB + (kb>>3) + kc)*outw + col0 + cc)*8);
      }
      gload_lds16(src, dst + (size_t)cid*16);
    }
  };

  f32x4 acc[4][2];
  #pragma unroll
  for (int i = 0; i < 4; i++)
    #pragma unroll
    for (int j = 0; j < 2; j++)
      #pragma unroll
      for (int q = 0; q < 4; q++) acc[i][j][q] = 0.f;

  STAGE(0, 0);
  for (int s = 0; s < nsteps; s++) {
    int cur = s & 1;
    if (s + 1 < nsteps) {
      STAGE(s + 1, cur ^ 1);
      asm volatile("s_waitcnt vmcnt(4)" ::: "memory");
    } else {
      asm volatile("s_waitcnt vmcnt(0)" ::: "memory");
    }
    __builtin_amdgcn_s_barrier();
    __builtin_amdgcn_sched_barrier(0);

    const u16* Alds = (const u16*)(lds + cur * 32768);
    const u16* Blds = (const u16*)(lds + cur * 32768 + 16384);

    half8 af[2][4];
    #pragma unroll
    for (int pl = 0; pl < 2; pl++)
      #pragma unroll
      for (int fr = 0; fr < 4; fr++) {
        int chunk = (pl*4 + lq)*128 + wr*64 + fr*16 + l15;
        af[pl][fr] = *reinterpret_cast<const half8*>(&Alds[(size_t)chunk*8]);
      }
    #pragma unroll
    for (int fc = 0; fc < 2; fc++) {
      int cc = wc*32 + fc*16 + l15;
      half8 b0 = *reinterpret_cast<const half8*>(&Blds[(size_t)((0*4 + lq)*128 + cc)*8]);
      half8 b1 = *reinterpret_cast<const half8*>(&Blds[(size_t)((1*4 + lq)*128 + cc)*8]);
      #pragma unroll
      for (int fr = 0; fr < 4; fr++) {
        acc[fr][fc] = __builtin_amdgcn_mfma_f32_16x16x32_f16(af[0][fr], b0, acc[fr][fc], 0, 0, 0);
        acc[fr][fc] = __builtin_amdgcn_mfma_f32_16x16x32_f16(af[1][fr], b0, acc[fr][fc], 0, 0, 0);
        acc[fr][fc] = __builtin_amdgcn_mfma_f32_16x16x32_f16(af[0][fr], b1, acc[fr][fc], 0, 0, 0);
      }
    }
    __builtin_amdgcn_sched_barrier(0);
    asm volatile("s_waitcnt lgkmcnt(0)" ::: "memory");
    __builtin_amdgcn_s_barrier();
  }

  float* pp = part + (size_t)z * sstride;
  #pragma unroll
  for (int fr = 0; fr < 4; fr++)
    #pragma unroll
    for (int fc = 0; fc < 2; fc++) {
      int col = col0 + wc*32 + fc*16 + l15;
      #pragma unroll
      for (int rr = 0; rr < 4; rr++) {
        int row = row0 + wr*64 + fr*16 + lq*4 + rr;
        pp[(size_t)row*outw + col] = acc[fr][fc][rr];
      }
    }
}

// -------- reduce split-K -> tiled fp16 planes --------------------------------
__global__ void k_reduce_split(const float* __restrict__ part,
                               const float* __restrict__ bias,
                               u16* __restrict__ ys) {
  int idx = blockIdx.x * 256 + threadIdx.x;
  int row = idx >> 7, cg = idx & 127;
  float4 s0 = {0,0,0,0}, s1 = {0,0,0,0};
  #pragma unroll
  for (int s = 0; s < 8; s++) {
    const float4* p = (const float4*)(part + (size_t)s*1048576 + (size_t)row*1024 + cg*8);
    float4 a = p[0], b = p[1];
    s0.x += a.x; s0.y += a.y; s0.z += a.z; s0.w += a.w;
    s1.x += b.x; s1.y += b.y; s1.z += b.z; s1.w += b.w;
  }
  float v[8] = {s0.x, s0.y, s0.z, s0.w, s1.x, s1.y, s1.z, s1.w};
  short8 o0, o1;
  #pragma unroll
  for (int e = 0; e < 8; e++) {
    float x = v[e] * (1.0f/2048.0f) + bias[cg*8 + e];
    x = fmaxf(x, 0.f) * 16.0f;
    u16 h0, h1;
    split2(x, h0, h1);
    o0[e] = (short)h0; o1[e] = (short)h1;
  }
  size_t base = ((size_t)cg * 1024 + row) * 8;
  *reinterpret_cast<short8*>(ys + base)               = o0;
  *reinterpret_cast<short8*>(ys + (size_t)1048576 + base) = o1;
}

// -------- fused heads finish: sum part + bias + softmax + decode + keys ----
__global__ __launch_bounds__(128) void k_headfin(const float* __restrict__ part,
                                                 const float* __restrict__ bcat,
                                                 const float* __restrict__ props,
                                                 float* __restrict__ cboxes,
                                                 u64* __restrict__ keys) {
  __shared__ float sc[512];
  __shared__ float red[128];
  int r = blockIdx.x;
  int j = threadIdx.x;
  int c0 = j * 4;
  float4 v = {0.f, 0.f, 0.f, 0.f};
  #pragma unroll
  for (int s = 0; s < 8; s++) {
    float4 p = *(const float4*)(part + (size_t)s*524288 + (size_t)r*512 + c0);
    v.x += p.x; v.y += p.y; v.z += p.z; v.w += p.w;
  }
  float4 bz = *(const float4*)(bcat + c0);
  sc[c0+0] = v.x * (1.0f/2048.0f) + bz.x;
  sc[c0+1] = v.y * (1.0f/2048.0f) + bz.y;
  sc[c0+2] = v.z * (1.0f/2048.0f) + bz.z;
  sc[c0+3] = v.w * (1.0f/2048.0f) + bz.w;
  __syncthreads();

  float lg = (j < NCLS) ? sc[j] : -3.4e38f;
  red[j] = lg;
  __syncthreads();
  for (int s = 64; s > 0; s >>= 1) {
    if (j < s) red[j] = fmaxf(red[j], red[j+s]);
    __syncthreads();
  }
  float mx = red[0];
  __syncthreads();
  float e = (j < NCLS) ? expf(lg - mx) : 0.f;
  red[j] = e;
  __syncthreads();
  for (int s = 64; s > 0; s >>= 1) {
    if (j < s) red[j] += red[j+s];
    __syncthreads();
  }
  float p = e / red[0];
  if (j >= 1 && j < NCLS) {
    float px1 = props[r*4+0], py1 = props[r*4+1];
    float px2 = props[r*4+2], py2 = props[r*4+3];
    float w = px2 - px1, h = py2 - py1;
    float cx = px1 + 0.5f*w, cy = py1 + 0.5f*h;
    float d0 = sc[91 + j*4 + 0];
    float d1 = sc[91 + j*4 + 1];
    float d2 = sc[91 + j*4 + 2];
    float d3 = sc[91 + j*4 + 3];
    float dx = d0 / 10.0f, dy = d1 / 10.0f;
    float dw = fminf(d2 / 5.0f, 4.135166556742356f);
    float dh = fminf(d3 / 5.0f, 4.135166556742356f);
    float pcx = dx*w + cx, pcy = dy*h + cy;
    float pw = expf(dw)*w, ph = expf(dh)*h;
    float bx1 = fminf(fmaxf(pcx - 0.5f*pw, 0.f), 1216.f);
    float by1 = fminf(fmaxf(pcy - 0.5f*ph, 0.f),  800.f);
    float bx2 = fminf(fmaxf(pcx + 0.5f*pw, 0.f), 1216.f);
    float by2 = fminf(fmaxf(pcy + 0.5f*ph, 0.f),  800.f);
    bool valid = (p > 0.05f) && ((bx2 - bx1) >= 0.01f) && ((by2 - by1) >= 0.01f);
    int b = r >> 8, n = r & 255;
    int cidx = n*90 + (j-1);
    size_t cb = (size_t)b*CAND + cidx;
    cboxes[cb*4+0] = bx1; cboxes[cb*4+1] = by1;
    cboxes[cb*4+2] = bx2; cboxes[cb*4+3] = by2;
    u64 key = 0ull;
    if (valid)
      key = (((u64)__float_as_uint(p)) << 32) | (u32)(~(u32)cidx);
    keys[cb] = key;
  }
}

// -------- per (batch,half): compact valid + bitonic sort desc, top1024 -----
#define SORTN 4096
__global__ __launch_bounds__(1024) void k_sort(const u64* __restrict__ keys,
                                               u64* __restrict__ sorted) {
  __shared__ u64 sk[SORTN];
  __shared__ int cnt;
  int t = threadIdx.x;
  int b = blockIdx.x >> 1, h = blockIdx.x & 1;
  if (t == 0) cnt = 0;
  __syncthreads();
  const u64* kb = keys + (size_t)b*CAND + (size_t)h*(CAND/2);
  for (int q = 0; q < 12; q++) {
    int idx = t + q*1024;
    if (idx < CAND/2) {
      u64 k = kb[idx];
      if (k) { int pos = atomicAdd(&cnt, 1); sk[pos] = k; }
    }
  }
  __syncthreads();
  int total = cnt;
  for (int s = t; s < SORTN; s += 1024)
    if (s >= total) sk[s] = 0ull;
  __syncthreads();
  for (int k = 2; k <= SORTN; k <<= 1) {
    for (int jj = k >> 1; jj > 0; jj >>= 1) {
      for (int i = t; i < SORTN; i += 1024) {
        int ixj = i ^ jj;
        if (ixj > i) {
          u64 a = sk[i], bb = sk[ixj];
          bool up = ((i & k) == 0);
          if (up ? (a < bb) : (a > bb)) { sk[i] = bb; sk[ixj] = a; }
        }
      }
      __syncthreads();
    }
  }
  sorted[((size_t)b*2 + h)*1024 + t] = sk[t];
}

// -------- per batch: merge halves, tiled greedy NMS, emit final 100 --------
__global__ __launch_bounds__(1024) void k_nms(const u64* __restrict__ sorted,
                                              const float* __restrict__ cboxes,
                                              float* __restrict__ out) {
  __shared__ u64 m[2048];
  __shared__ float sX1[1024], sY1[1024], sX2[1024], sY2[1024], sAR[1024];
  __shared__ int keepL[1024];
  __shared__ int wsum[16];
  int t = threadIdx.x;
  int b = blockIdx.x;
  m[t]        = sorted[((size_t)b*2 + 0)*1024 + t];
  m[2047 - t] = sorted[((size_t)b*2 + 1)*1024 + t];
  __syncthreads();
  for (int lg = 10; lg >= 0; lg--) {
    int jj = 1 << lg;
    int pos = ((t >> lg) << (lg+1)) + (t & (jj-1));
    u64 a = m[pos], bb = m[pos + jj];
    if (a < bb) { m[pos] = bb; m[pos + jj] = a; }
    __syncthreads();
  }
  u64 key = m[t];
  bool valid = key != 0ull;
  float score = __uint_as_float((u32)(key >> 32));
  u32 cidx = ~((u32)(key & 0xFFFFFFFFu));
  int label = valid ? (int)(cidx % 90u) + 1 : 0;
  float cb0 = 0.f, cb1 = 0.f, cb2 = 0.f, cb3 = 0.f;
  if (valid) {
    size_t cb = ((size_t)b*CAND + cidx) * 4;
    cb0 = cboxes[cb+0]; cb1 = cboxes[cb+1];
    cb2 = cboxes[cb+2]; cb3 = cboxes[cb+3];
  }
  float off = (float)label * 1218.0f;
  float ox1 = cb0 + off, oy1 = cb1 + off;
  float ox2 = cb2 + off, oy2 = cb3 + off;
  float area = (ox2 - ox1) * (oy2 - oy1);
  sX1[t] = ox1; sY1[t] = oy1; sX2[t] = ox2; sY2[t] = oy2; sAR[t] = area;
  keepL[t] = valid ? 1 : 0;
  __syncthreads();

  int wid = t >> 6, lane = t & 63;
  for (int tile = 0; tile < 16; tile++) {
    if (wid == 0) {
      int idx = tile*64 + lane;
      bool kp = keepL[idx] != 0;
      float bx1 = sX1[idx], by1 = sY1[idx], bx2 = sX2[idx], by2 = sY2[idx], ba = sAR[idx];
      u64 alive = __ballot(kp);
      #pragma unroll 1
      for (int i = 0; i < 63; i++) {
        if ((alive >> i) & 1ull) {
          int ii = tile*64 + i;
          float ltx = fmaxf(sX1[ii], bx1), lty = fmaxf(sY1[ii], by1);
          float rbx = fminf(sX2[ii], bx2), rby = fminf(sY2[ii], by2);
          float iw = fmaxf(rbx - ltx, 0.f), ih = fmaxf(rby - lty, 0.f);
          float inter = iw * ih;
          float iou = inter / (sAR[ii] + ba - inter + 1e-9f);
          if (lane > i && iou > 0.5f) kp = false;
        }
        alive = __ballot(kp);
      }
      keepL[idx] = kp ? 1 : 0;
    }
    __syncthreads();
    if (t >= (tile+1)*64) {
      bool kp = keepL[t] != 0;
      if (kp) {
        #pragma unroll 1
        for (int i = tile*64; i < tile*64 + 64; i++) {
          if (keepL[i]) {
            float ltx = fmaxf(sX1[i], ox1), lty = fmaxf(sY1[i], oy1);
            float rbx = fminf(sX2[i], ox2), rby = fminf(sY2[i], oy2);
            float iw = fmaxf(rbx - ltx, 0.f), ih = fmaxf(rby - lty, 0.f);
            float inter = iw * ih;
            float iou = inter / (sAR[i] + area - inter + 1e-9f);
            if (iou > 0.5f) { kp = false; }
          }
        }
        if (!kp) keepL[t] = 0;
      }
    }
    __syncthreads();
  }

  bool keep = keepL[t] != 0;
  u64 bal = __ballot(keep);
  int wpre = __popcll(bal & ((1ull << lane) - 1ull));
  if (lane == 0) wsum[wid] = __popcll(bal);
  __syncthreads();
  int offn = 0, KT = 0;
  for (int q = 0; q < 16; q++) {
    int v = wsum[q];
    if (q < wid) offn += v;
    KT += v;
  }
  int rank = offn + wpre;
  float* outB = out;
  float* outS = out + 1600;
  float* outL = out + 2000;
  if (keep && rank < 100) {
    size_t s = (size_t)b*100 + rank;
    outB[s*4+0] = cb0; outB[s*4+1] = cb1;
    outB[s*4+2] = cb2; outB[s*4+3] = cb3;
    outS[s] = score; outL[s] = (float)label;
  }
  if (t < 100 && t >= KT) {
    size_t s = (size_t)b*100 + t;
    outB[s*4+0] = 0.f; outB[s*4+1] = 0.f; outB[s*4+2] = 0.f; outB[s*4+3] = 0.f;
    outS[s] = 0.f; outL[s] = 0.f;
  }
}

extern "C" void kernel_launch(void* const* d_in, const int* in_sizes, int n_in,
                              void* d_out, int out_size, void* d_ws, size_t ws_size,
                              hipStream_t stream) {
  (void)in_sizes; (void)n_in; (void)out_size; (void)ws_size;
  const float* feat  = (const float*)d_in[0];
  const float* props = (const float*)d_in[1];
  const float* W6 = (const float*)d_in[2];
  const float* b6 = (const float*)d_in[3];
  const float* W7 = (const float*)d_in[4];
  const float* b7 = (const float*)d_in[5];
  const float* Wc = (const float*)d_in[6];
  const float* bc = (const float*)d_in[7];
  const float* Wb = (const float*)d_in[8];
  const float* bb = (const float*)d_in[9];
  float* out = (float*)d_out;
  char* ws = (char*)d_ws;

  float* featT  = (float*)(ws);                        // 62,259,200 B
  u16*   Xs2    = (u16*)  (ws + 62259200);             // 51,380,224 B (tiled)
  float* part   = (float*)(ws);                        // 33,554,432 B (8 slices)
  u16*   Y1s2   = (u16*)  (ws + 33554432);             //  4,194,304 B (tiled)
  u16*   Y2s2   = (u16*)  (ws + 37748736);             //  4,194,304 B (tiled)
  u16*   W7t    = (u16*)  (ws + 41943040);             //  4,194,304 B (tiled B)
  u16*   Wcatt  = (u16*)  (ws + 46137344);             //  2,097,152 B (tiled B)
  float* bcat   = (float*)(ws + 48234496);             //      2,048 B
  float* cboxes = (float*)(ws + 50102272);             //  1,474,560 B
  u64*   keys   = (u64*)  (ws + 51576832);             //    737,280 B
  u64*   sorted = (u64*)  (ws + 52314112);             //     65,536 B

  dim3 gT(475, 8, 4);
  k_transpose<<<gT, 256, 0, stream>>>(feat, featT);
  k_roialign<<<1024, 256, 0, stream>>>(featT, props, Xs2);
  // packs (outputs live in dead-featT region -> must run after roialign)
  k_packs<<<768, 256, 0, stream>>>(W7, W7t, Wc, Wb, bc, bb, Wcatt, bcat);

  // FC6: K=12544 (kg=1568), split-K=8, 49 steps/slice, 512 blocks (2/CU)
  k_gemm_f16<<<512, 512, 0, stream>>>(Xs2, W6, part, DIN/8, 49, 8, 1024, 1048576);
  k_reduce_split<<<512, 256, 0, stream>>>(part, b6, Y1s2);
  // FC7: K=1024, split-K=8, 4 steps/slice, fp16-B path
  k_gemm_f16b<<<512, 512, 0, stream>>>(Y1s2, W7t, part, 128, 128, 4, 8, 1024, 1048576);
  k_reduce_split<<<512, 256, 0, stream>>>(part, b7, Y2s2);
  // heads: M=1024, N=512(padded 455), K=1024, split-K=8, fp16-B path
  k_gemm_f16b<<<256, 512, 0, stream>>>(Y2s2, Wcatt, part, 128, 128, 4, 4, 512, 524288);
  // fused heads-finish (sum + bias + softmax + decode + keys)
  k_headfin<<<1024, 128, 0, stream>>>(part, bcat, props, cboxes, keys);

  k_sort<<<8, 1024, 0, stream>>>(keys, sorted);
  k_nms<<<4, 1024, 0, stream>>>(sorted, cboxes, out);
}

// Round 14
// 337.037 us; speedup vs baseline: 1.0827x; 1.0194x over previous
//
#include <hip/hip_runtime.h>
#include <hip/hip_bf16.h>
#include <stdint.h>

#define B_    4
#define N_    256
#define C_    256
#define FH_   100
#define FW_   152
#define P_HW  (FH_*FW_)      // 15200
#define NCLS  91
#define CAND  23040          // N_*90
#define DIN   12544
#define PRE   1024

typedef unsigned long long u64;
typedef unsigned int u32;
typedef unsigned short u16;
typedef __attribute__((ext_vector_type(8))) _Float16 half8;
typedef __attribute__((ext_vector_type(8))) short short8;
typedef __attribute__((ext_vector_type(4))) float f32x4;

__device__ inline u16 h2bits(_Float16 h) { return *reinterpret_cast<u16*>(&h); }

__device__ inline void split2(float v, u16& b0, u16& b1) {
  _Float16 h0 = (_Float16)v;
  float r = v - (float)h0;
  _Float16 h1 = (_Float16)r;
  b0 = h2bits(h0); b1 = h2bits(h1);
}

__device__ inline void gload_lds16(const void* g, void* l) {
  __builtin_amdgcn_global_load_lds(
      (const __attribute__((address_space(1))) void*)g,
      (__attribute__((address_space(3))) void*)l, 16, 0, 0);
}

// ---------------- feature transpose (B,C,H,W) -> (B,H,W,C) ----------------
__global__ void k_transpose(const float* __restrict__ in, float* __restrict__ out) {
  __shared__ float t[32][33];
  int b  = blockIdx.z;
  int c0 = blockIdx.y * 32;
  int p0 = blockIdx.x * 32;
  int tx = threadIdx.x & 31, ty = threadIdx.x >> 5;
  const float* inb = in  + (size_t)b * C_ * P_HW;
  float*       ob  = out + (size_t)b * P_HW * C_;
  #pragma unroll
  for (int q = 0; q < 4; q++)
    t[ty + q*8][tx] = inb[(size_t)(c0 + ty + q*8) * P_HW + p0 + tx];
  __syncthreads();
  #pragma unroll
  for (int q = 0; q < 4; q++)
    ob[(size_t)(p0 + ty + q*8) * C_ + c0 + tx] = t[tx][ty + q*8];
}

// -------- packs: W7 (blocks 0..511) + heads Wc|Wb (512..767) ---------------
__global__ void k_packs(const float* __restrict__ W7, u16* __restrict__ W7t,
                        const float* __restrict__ Wc, const float* __restrict__ Wb,
                        const float* __restrict__ bc, const float* __restrict__ bb,
                        u16* __restrict__ Wcatt, float* __restrict__ bcat) {
  int bid = blockIdx.x;
  int tid = threadIdx.x;
  if (bid < 512) {
    int idx = bid * 256 + tid;                 // 131072 = 128 ko x 1024 col
    int col = idx & 1023, ko = idx >> 10;
    short8 c0v, c1v;
    #pragma unroll
    for (int e = 0; e < 8; e++) {
      float w = W7[(size_t)(ko*8 + e)*1024 + col] * 128.0f;
      u16 h0, h1;
      split2(w, h0, h1);
      c0v[e] = (short)h0; c1v[e] = (short)h1;
    }
    *reinterpret_cast<short8*>(W7t + ((size_t)ko*1024 + col)*8)         = c0v;
    *reinterpret_cast<short8*>(W7t + ((size_t)(128 + ko)*1024 + col)*8) = c1v;
  } else {
    int idx = (bid - 512) * 256 + tid;         // 65536 = 128 ko x 512 col
    int col = idx & 511, ko = idx >> 9;
    short8 c0v, c1v;
    #pragma unroll
    for (int e = 0; e < 8; e++) {
      int k = ko*8 + e;
      float w = 0.f;
      if (col < 91)       w = Wc[(size_t)k*91 + col];
      else if (col < 455) w = Wb[(size_t)k*364 + (col - 91)];
      w *= 128.0f;
      u16 h0, h1;
      split2(w, h0, h1);
      c0v[e] = (short)h0; c1v[e] = (short)h1;
    }
    *reinterpret_cast<short8*>(Wcatt + ((size_t)ko*512 + col)*8)         = c0v;
    *reinterpret_cast<short8*>(Wcatt + ((size_t)(128 + ko)*512 + col)*8) = c1v;
    if (idx < 512) {
      float bv = 0.f;
      if (idx < 91)       bv = bc[idx];
      else if (idx < 455) bv = bb[idx - 91];
      bcat[idx] = bv;
    }
  }
}

// ------- roi align -> Xt [2 planes][DIN/8][1024 rows][8] fp16 of (X*16) ----
__global__ __launch_bounds__(256, 8) void k_roialign(const float* __restrict__ featT,
                                                     const float* __restrict__ props,
                                                     u16* __restrict__ Xs) {
  __shared__ float sPW[196][8];     // {p00,p01,p10,p11,w00,w01,w10,w11}
  __shared__ float cellv[32][51];   // [ch-in-group][cell]
  int bid = blockIdx.x;
  int xcd = bid & 7;
  int b = xcd >> 1;
  int n = ((bid >> 3) << 1) | (xcd & 1);
  int r = (b << 8) | n;                 // bijective 0..1023, XCD-batch affine
  int tid = threadIdx.x;

  float x1 = props[r*4+0], y1 = props[r*4+1];
  float x2 = props[r*4+2], y2 = props[r*4+3];
  float x1s = x1 * 0.125f, y1s = y1 * 0.125f;
  float x2s = x2 * 0.125f, y2s = y2 * 0.125f;
  float rw = fmaxf(x2s - x1s, 1.0f);
  float rh = fmaxf(y2s - y1s, 1.0f);
  float rwd = rw / 7.0f, rhd = rh / 7.0f;

  if (tid < 196) {
    int cell = tid >> 2, s = tid & 3;
    int py = cell / 7, px = cell % 7;
    int sy = s >> 1, sx = s & 1;
    float gqy = (float)py + 0.25f + 0.5f * (float)sy;
    float gqx = (float)px + 0.25f + 0.5f * (float)sx;
    float gy = fminf(fmaxf(y1s + rhd * gqy, 0.0f), 99.0f);
    float gx = fminf(fmaxf(x1s + rwd * gqx, 0.0f), 151.0f);
    float y0f = floorf(gy), x0f = floorf(gx);
    float ly = gy - y0f, lx = gx - x0f;
    int y0i = (int)y0f;
    int y1i = (int)fminf(y0f + 1.0f, 99.0f);
    int x0i = (int)x0f;
    int x1i = (int)fminf(x0f + 1.0f, 151.0f);
    sPW[tid][0] = __int_as_float((y0i * FW_ + x0i) * 256);
    sPW[tid][1] = __int_as_float((y0i * FW_ + x1i) * 256);
    sPW[tid][2] = __int_as_float((y1i * FW_ + x0i) * 256);
    sPW[tid][3] = __int_as_float((y1i * FW_ + x1i) * 256);
    sPW[tid][4] = (1.f-ly)*(1.f-lx);
    sPW[tid][5] = (1.f-ly)*lx;
    sPW[tid][6] = ly*(1.f-lx);
    sPW[tid][7] = ly*lx;
  }
  __syncthreads();

  int c32 = tid & 31;
  int slot = tid >> 5;
  const size_t PLS = (size_t)(DIN/8) * 1024 * 8;

  for (int g = 0; g < 8; g++) {
    const float* fb = featT + (size_t)b * P_HW * C_ + g*32 + c32;
    for (int cell = slot; cell < 49; cell += 8) {
      float acc = 0.f;
      #pragma unroll
      for (int s = 0; s < 4; s++) {
        int cs = cell*4 + s;
        float4 pv = *(const float4*)&sPW[cs][0];
        float4 wv = *(const float4*)&sPW[cs][4];
        acc += wv.x * fb[__float_as_int(pv.x)]
             + wv.y * fb[__float_as_int(pv.y)]
             + wv.z * fb[__float_as_int(pv.z)]
             + wv.w * fb[__float_as_int(pv.w)];
      }
      cellv[c32][cell] = acc * 4.0f;   // 0.25 (avg) * 16 (prescale)
    }
    __syncthreads();
    if (tid < 196) {
      short8 v0, v1;
      #pragma unroll
      for (int e = 0; e < 8; e++) {
        int kl = tid*8 + e;
        int chl = kl / 49;
        int cell = kl - chl*49;
        float v = cellv[chl][cell];
        u16 h0, h1;
        split2(v, h0, h1);
        v0[e] = (short)h0; v1[e] = (short)h1;
      }
      size_t cg = (size_t)g*196 + tid;
      size_t base = (cg * 1024 + r) * 8;
      *reinterpret_cast<short8*>(Xs + base)       = v0;
      *reinterpret_cast<short8*>(Xs + PLS + base) = v1;
    }
    __syncthreads();
  }
}

// -------- FC6 MFMA GEMM: 128x256 tile, single-barrier 3-buffer pipeline ----
// fp32 via fp16 2-plane 3-pass. 8 waves, wave tile 128x32 (fr=8, fc=2).
// T3/T4: 3 LDS buffers (3 x 48KB), stage-ahead-2, ONE s_barrier per step,
// counted vmcnt(12) (never drained to 0 in main loop).
// WAR safety: STAGE(s+2) overwrites the buffer read at step s-1; every wave
// at the step-s barrier has already lgkm-consumed those reads (MFMA issue
// implies lgkmcnt wait), so one barrier suffices.
__global__ __launch_bounds__(512) void k_gemm_fc6(
    const u16* __restrict__ As, const float* __restrict__ Bw,
    float* __restrict__ part, int kg, int nsteps) {
  __shared__ __align__(16) char lds[147456];   // 3 x (A 16KB + B 32KB)
  int tid = threadIdx.x;
  int wid = tid >> 6, lane = tid & 63;
  int l15 = lane & 15, lq = lane >> 4;
  int bid = blockIdx.x;
  int z = bid & 7, xy = bid >> 3;              // one K-slice per XCD
  int col0 = (xy & 3) * 256, row0 = (xy >> 2) * 128;
  int kbase0 = z * nsteps * 32;

  auto STAGE = [&](int s, int bsel) {
    int kb = kbase0 + s * 32;
    char* dst = lds + (size_t)bsel * 49152;
    #pragma unroll
    for (int j = 0; j < 6; j++) {
      int cid = tid + j*512;
      const char* src;
      if (j < 2) {
        // A: 1024 chunks = [2 pl][4 kc][128 rows]
        int pl = cid >> 9;
        int kc = (cid >> 7) & 3, rr = cid & 127;
        src = (const char*)(As + ((size_t)(pl*kg + (kb>>3) + kc)*1024 + row0 + rr)*8);
      } else {
        // B: 2048 chunks = [32 k][64 col-chunks of 4 f32], XOR-swizzled
        int cid2 = cid - 1024;
        int kk = cid2 >> 6, c4 = cid2 & 63;
        int col = (c4*4) ^ (((kk >> 3) & 1) << 4);
        src = (const char*)(Bw + (size_t)(kb + kk)*1024 + col0 + col);
      }
      gload_lds16(src, dst + (size_t)cid*16);
    }
  };

  f32x4 acc[8][2];
  #pragma unroll
  for (int i = 0; i < 8; i++)
    #pragma unroll
    for (int j = 0; j < 2; j++)
      #pragma unroll
      for (int q = 0; q < 4; q++) acc[i][j][q] = 0.f;

  STAGE(0, 0);
  if (nsteps > 1) STAGE(1, 1);
  int rb = 0, tb = 2;                          // read-buf, stage-target buf
  for (int s = 0; s < nsteps; s++) {
    // barrier: all waves done reading buf tb (read at step s-1)
    __builtin_amdgcn_sched_barrier(0);
    __builtin_amdgcn_s_barrier();
    __builtin_amdgcn_sched_barrier(0);
    if (s + 2 < nsteps) STAGE(s + 2, tb);
    // wait for stage s only; stages s+1 (and s+2 if issued) stay in flight
    if (s + 2 < nsteps)      asm volatile("s_waitcnt vmcnt(12)" ::: "memory");
    else if (s + 1 < nsteps) asm volatile("s_waitcnt vmcnt(6)" ::: "memory");
    else                     asm volatile("s_waitcnt vmcnt(0)" ::: "memory");
    __builtin_amdgcn_sched_barrier(0);

    const u16*   Alds = (const u16*)(lds + (size_t)rb * 49152);
    const float* Blds = (const float*)(lds + (size_t)rb * 49152 + 16384);

    // A fragments: whole 128-row panel (2 planes x 8 row-frags)
    half8 af[2][8];
    #pragma unroll
    for (int pl = 0; pl < 2; pl++)
      #pragma unroll
      for (int fr = 0; fr < 8; fr++) {
        int chunk = (pl*4 + lq)*128 + fr*16 + l15;
        af[pl][fr] = *reinterpret_cast<const half8*>(&Alds[(size_t)chunk*8]);
      }
    int cxor = (lq & 1) << 4;
    __builtin_amdgcn_s_setprio(1);
    #pragma unroll
    for (int fc = 0; fc < 2; fc++) {
      int colx = (wid*32 + fc*16 + l15) ^ cxor;
      half8 b0, b1;
      #pragma unroll
      for (int j = 0; j < 8; j++) {
        float w = Blds[(lq*8 + j)*256 + colx] * 128.0f;
        _Float16 h0 = (_Float16)w;
        float rres = w - (float)h0;
        b0[j] = h0; b1[j] = (_Float16)rres;
      }
      #pragma unroll
      for (int fr = 0; fr < 8; fr++) {
        acc[fr][fc] = __builtin_amdgcn_mfma_f32_16x16x32_f16(af[0][fr], b0, acc[fr][fc], 0, 0, 0);
        acc[fr][fc] = __builtin_amdgcn_mfma_f32_16x16x32_f16(af[1][fr], b0, acc[fr][fc], 0, 0, 0);
        acc[fr][fc] = __builtin_amdgcn_mfma_f32_16x16x32_f16(af[0][fr], b1, acc[fr][fc], 0, 0, 0);
      }
    }
    __builtin_amdgcn_s_setprio(0);
    __builtin_amdgcn_sched_barrier(0);
    rb = (rb == 2) ? 0 : rb + 1;
    tb = (tb == 2) ? 0 : tb + 1;
  }

  float* pp = part + (size_t)z * 1048576;
  #pragma unroll
  for (int fr = 0; fr < 8; fr++)
    #pragma unroll
    for (int fc = 0; fc < 2; fc++) {
      int col = col0 + wid*32 + fc*16 + l15;
      #pragma unroll
      for (int rr = 0; rr < 4; rr++) {
        int row = row0 + fr*16 + lq*4 + rr;
        pp[(size_t)row*1024 + col] = acc[fr][fc][rr];
      }
    }
}

// -------- MFMA GEMM, pre-split fp16 2-plane B (FC7 / heads) ---------------
__global__ __launch_bounds__(512) void k_gemm_f16b(
    const u16* __restrict__ As, const u16* __restrict__ Bt,
    float* __restrict__ part, int kgA, int kgB, int nsteps, int nct, int outw,
    size_t sstride) {
  __shared__ __align__(16) char lds[65536];
  int tid = threadIdx.x;
  int wid = tid >> 6, lane = tid & 63;
  int l15 = lane & 15, lq = lane >> 4;
  int bid = blockIdx.x;
  int z = bid & 7, xy = bid >> 3;
  int col0 = (xy % nct) * 128, row0 = (xy / nct) * 128;
  int wr = wid >> 2, wc = wid & 3;
  int kbase0 = z * nsteps * 32;

  auto STAGE = [&](int s, int bsel) {
    int kb = kbase0 + s * 32;
    char* dst = lds + bsel * 32768;
    #pragma unroll
    for (int j = 0; j < 4; j++) {
      int cid = tid + j*512;
      const char* src;
      if (j < 2) {
        int pl = cid >> 9;
        int kc = (cid >> 7) & 3, rr = cid & 127;
        src = (const char*)(As + ((size_t)(pl*kgA + (kb>>3) + kc)*1024 + row0 + rr)*8);
      } else {
        int cid2 = cid - 1024;
        int pl = cid2 >> 9;
        int kc = (cid2 >> 7) & 3, cc = cid2 & 127;
        src = (const char*)(Bt + ((size_t)(pl*kgB + (kb>>3) + kc)*outw + col0 + cc)*8);
      }
      gload_lds16(src, dst + (size_t)cid*16);
    }
  };

  f32x4 acc[4][2];
  #pragma unroll
  for (int i = 0; i < 4; i++)
    #pragma unroll
    for (int j = 0; j < 2; j++)
      #pragma unroll
      for (int q = 0; q < 4; q++) acc[i][j][q] = 0.f;

  STAGE(0, 0);
  for (int s = 0; s < nsteps; s++) {
    int cur = s & 1;
    if (s + 1 < nsteps) {
      STAGE(s + 1, cur ^ 1);
      asm volatile("s_waitcnt vmcnt(4)" ::: "memory");
    } else {
      asm volatile("s_waitcnt vmcnt(0)" ::: "memory");
    }
    __builtin_amdgcn_s_barrier();
    __builtin_amdgcn_sched_barrier(0);

    const u16* Alds = (const u16*)(lds + cur * 32768);
    const u16* Blds = (const u16*)(lds + cur * 32768 + 16384);

    half8 af[2][4];
    #pragma unroll
    for (int pl = 0; pl < 2; pl++)
      #pragma unroll
      for (int fr = 0; fr < 4; fr++) {
        int chunk = (pl*4 + lq)*128 + wr*64 + fr*16 + l15;
        af[pl][fr] = *reinterpret_cast<const half8*>(&Alds[(size_t)chunk*8]);
      }
    #pragma unroll
    for (int fc = 0; fc < 2; fc++) {
      int cc = wc*32 + fc*16 + l15;
      half8 b0 = *reinterpret_cast<const half8*>(&Blds[(size_t)((0*4 + lq)*128 + cc)*8]);
      half8 b1 = *reinterpret_cast<const half8*>(&Blds[(size_t)((1*4 + lq)*128 + cc)*8]);
      #pragma unroll
      for (int fr = 0; fr < 4; fr++) {
        acc[fr][fc] = __builtin_amdgcn_mfma_f32_16x16x32_f16(af[0][fr], b0, acc[fr][fc], 0, 0, 0);
        acc[fr][fc] = __builtin_amdgcn_mfma_f32_16x16x32_f16(af[1][fr], b0, acc[fr][fc], 0, 0, 0);
        acc[fr][fc] = __builtin_amdgcn_mfma_f32_16x16x32_f16(af[0][fr], b1, acc[fr][fc], 0, 0, 0);
      }
    }
    __builtin_amdgcn_sched_barrier(0);
    asm volatile("s_waitcnt lgkmcnt(0)" ::: "memory");
    __builtin_amdgcn_s_barrier();
  }

  float* pp = part + (size_t)z * sstride;
  #pragma unroll
  for (int fr = 0; fr < 4; fr++)
    #pragma unroll
    for (int fc = 0; fc < 2; fc++) {
      int col = col0 + wc*32 + fc*16 + l15;
      #pragma unroll
      for (int rr = 0; rr < 4; rr++) {
        int row = row0 + wr*64 + fr*16 + lq*4 + rr;
        pp[(size_t)row*outw + col] = acc[fr][fc][rr];
      }
    }
}

// -------- reduce split-K -> tiled fp16 planes --------------------------------
__global__ void k_reduce_split(const float* __restrict__ part,
                               const float* __restrict__ bias,
                               u16* __restrict__ ys) {
  int idx = blockIdx.x * 256 + threadIdx.x;
  int row = idx >> 7, cg = idx & 127;
  float4 s0 = {0,0,0,0}, s1 = {0,0,0,0};
  #pragma unroll
  for (int s = 0; s < 8; s++) {
    const float4* p = (const float4*)(part + (size_t)s*1048576 + (size_t)row*1024 + cg*8);
    float4 a = p[0], b = p[1];
    s0.x += a.x; s0.y += a.y; s0.z += a.z; s0.w += a.w;
    s1.x += b.x; s1.y += b.y; s1.z += b.z; s1.w += b.w;
  }
  float v[8] = {s0.x, s0.y, s0.z, s0.w, s1.x, s1.y, s1.z, s1.w};
  short8 o0, o1;
  #pragma unroll
  for (int e = 0; e < 8; e++) {
    float x = v[e] * (1.0f/2048.0f) + bias[cg*8 + e];
    x = fmaxf(x, 0.f) * 16.0f;
    u16 h0, h1;
    split2(x, h0, h1);
    o0[e] = (short)h0; o1[e] = (short)h1;
  }
  size_t base = ((size_t)cg * 1024 + row) * 8;
  *reinterpret_cast<short8*>(ys + base)               = o0;
  *reinterpret_cast<short8*>(ys + (size_t)1048576 + base) = o1;
}

// -------- fused heads finish: sum part + bias + softmax + decode + keys ----
__global__ __launch_bounds__(128) void k_headfin(const float* __restrict__ part,
                                                 const float* __restrict__ bcat,
                                                 const float* __restrict__ props,
                                                 float* __restrict__ cboxes,
                                                 u64* __restrict__ keys) {
  __shared__ float sc[512];
  __shared__ float red[128];
  int r = blockIdx.x;
  int j = threadIdx.x;
  int c0 = j * 4;
  float4 v = {0.f, 0.f, 0.f, 0.f};
  #pragma unroll
  for (int s = 0; s < 8; s++) {
    float4 p = *(const float4*)(part + (size_t)s*524288 + (size_t)r*512 + c0);
    v.x += p.x; v.y += p.y; v.z += p.z; v.w += p.w;
  }
  float4 bz = *(const float4*)(bcat + c0);
  sc[c0+0] = v.x * (1.0f/2048.0f) + bz.x;
  sc[c0+1] = v.y * (1.0f/2048.0f) + bz.y;
  sc[c0+2] = v.z * (1.0f/2048.0f) + bz.z;
  sc[c0+3] = v.w * (1.0f/2048.0f) + bz.w;
  __syncthreads();

  float lg = (j < NCLS) ? sc[j] : -3.4e38f;
  red[j] = lg;
  __syncthreads();
  for (int s = 64; s > 0; s >>= 1) {
    if (j < s) red[j] = fmaxf(red[j], red[j+s]);
    __syncthreads();
  }
  float mx = red[0];
  __syncthreads();
  float e = (j < NCLS) ? expf(lg - mx) : 0.f;
  red[j] = e;
  __syncthreads();
  for (int s = 64; s > 0; s >>= 1) {
    if (j < s) red[j] += red[j+s];
    __syncthreads();
  }
  float p = e / red[0];
  if (j >= 1 && j < NCLS) {
    float px1 = props[r*4+0], py1 = props[r*4+1];
    float px2 = props[r*4+2], py2 = props[r*4+3];
    float w = px2 - px1, h = py2 - py1;
    float cx = px1 + 0.5f*w, cy = py1 + 0.5f*h;
    float d0 = sc[91 + j*4 + 0];
    float d1 = sc[91 + j*4 + 1];
    float d2 = sc[91 + j*4 + 2];
    float d3 = sc[91 + j*4 + 3];
    float dx = d0 / 10.0f, dy = d1 / 10.0f;
    float dw = fminf(d2 / 5.0f, 4.135166556742356f);
    float dh = fminf(d3 / 5.0f, 4.135166556742356f);
    float pcx = dx*w + cx, pcy = dy*h + cy;
    float pw = expf(dw)*w, ph = expf(dh)*h;
    float bx1 = fminf(fmaxf(pcx - 0.5f*pw, 0.f), 1216.f);
    float by1 = fminf(fmaxf(pcy - 0.5f*ph, 0.f),  800.f);
    float bx2 = fminf(fmaxf(pcx + 0.5f*pw, 0.f), 1216.f);
    float by2 = fminf(fmaxf(pcy + 0.5f*ph, 0.f),  800.f);
    bool valid = (p > 0.05f) && ((bx2 - bx1) >= 0.01f) && ((by2 - by1) >= 0.01f);
    int b = r >> 8, n = r & 255;
    int cidx = n*90 + (j-1);
    size_t cb = (size_t)b*CAND + cidx;
    cboxes[cb*4+0] = bx1; cboxes[cb*4+1] = by1;
    cboxes[cb*4+2] = bx2; cboxes[cb*4+3] = by2;
    u64 key = 0ull;
    if (valid)
      key = (((u64)__float_as_uint(p)) << 32) | (u32)(~(u32)cidx);
    keys[cb] = key;
  }
}

// -------- per (batch,half): compact valid + bitonic sort desc, top1024 -----
#define SORTN 4096
__global__ __launch_bounds__(1024) void k_sort(const u64* __restrict__ keys,
                                               u64* __restrict__ sorted) {
  __shared__ u64 sk[SORTN];
  __shared__ int cnt;
  int t = threadIdx.x;
  int b = blockIdx.x >> 1, h = blockIdx.x & 1;
  if (t == 0) cnt = 0;
  __syncthreads();
  const u64* kb = keys + (size_t)b*CAND + (size_t)h*(CAND/2);
  for (int q = 0; q < 12; q++) {
    int idx = t + q*1024;
    if (idx < CAND/2) {
      u64 k = kb[idx];
      if (k) { int pos = atomicAdd(&cnt, 1); sk[pos] = k; }
    }
  }
  __syncthreads();
  int total = cnt;
  for (int s = t; s < SORTN; s += 1024)
    if (s >= total) sk[s] = 0ull;
  __syncthreads();
  for (int k = 2; k <= SORTN; k <<= 1) {
    for (int jj = k >> 1; jj > 0; jj >>= 1) {
      for (int i = t; i < SORTN; i += 1024) {
        int ixj = i ^ jj;
        if (ixj > i) {
          u64 a = sk[i], bb = sk[ixj];
          bool up = ((i & k) == 0);
          if (up ? (a < bb) : (a > bb)) { sk[i] = bb; sk[ixj] = a; }
        }
      }
      __syncthreads();
    }
  }
  sorted[((size_t)b*2 + h)*1024 + t] = sk[t];
}

// -------- per batch: merge halves, tiled greedy NMS, emit final 100 --------
__global__ __launch_bounds__(1024) void k_nms(const u64* __restrict__ sorted,
                                              const float* __restrict__ cboxes,
                                              float* __restrict__ out) {
  __shared__ u64 m[2048];
  __shared__ float sX1[1024], sY1[1024], sX2[1024], sY2[1024], sAR[1024];
  __shared__ int keepL[1024];
  __shared__ int wsum[16];
  int t = threadIdx.x;
  int b = blockIdx.x;
  m[t]        = sorted[((size_t)b*2 + 0)*1024 + t];
  m[2047 - t] = sorted[((size_t)b*2 + 1)*1024 + t];
  __syncthreads();
  for (int lg = 10; lg >= 0; lg--) {
    int jj = 1 << lg;
    int pos = ((t >> lg) << (lg+1)) + (t & (jj-1));
    u64 a = m[pos], bb = m[pos + jj];
    if (a < bb) { m[pos] = bb; m[pos + jj] = a; }
    __syncthreads();
  }
  u64 key = m[t];
  bool valid = key != 0ull;
  float score = __uint_as_float((u32)(key >> 32));
  u32 cidx = ~((u32)(key & 0xFFFFFFFFu));
  int label = valid ? (int)(cidx % 90u) + 1 : 0;
  float cb0 = 0.f, cb1 = 0.f, cb2 = 0.f, cb3 = 0.f;
  if (valid) {
    size_t cb = ((size_t)b*CAND + cidx) * 4;
    cb0 = cboxes[cb+0]; cb1 = cboxes[cb+1];
    cb2 = cboxes[cb+2]; cb3 = cboxes[cb+3];
  }
  float off = (float)label * 1218.0f;
  float ox1 = cb0 + off, oy1 = cb1 + off;
  float ox2 = cb2 + off, oy2 = cb3 + off;
  float area = (ox2 - ox1) * (oy2 - oy1);
  sX1[t] = ox1; sY1[t] = oy1; sX2[t] = ox2; sY2[t] = oy2; sAR[t] = area;
  keepL[t] = valid ? 1 : 0;
  __syncthreads();

  int wid = t >> 6, lane = t & 63;
  for (int tile = 0; tile < 16; tile++) {
    if (wid == 0) {
      int idx = tile*64 + lane;
      bool kp = keepL[idx] != 0;
      float bx1 = sX1[idx], by1 = sY1[idx], bx2 = sX2[idx], by2 = sY2[idx], ba = sAR[idx];
      u64 alive = __ballot(kp);
      #pragma unroll 1
      for (int i = 0; i < 63; i++) {
        if ((alive >> i) & 1ull) {
          int ii = tile*64 + i;
          float ltx = fmaxf(sX1[ii], bx1), lty = fmaxf(sY1[ii], by1);
          float rbx = fminf(sX2[ii], bx2), rby = fminf(sY2[ii], by2);
          float iw = fmaxf(rbx - ltx, 0.f), ih = fmaxf(rby - lty, 0.f);
          float inter = iw * ih;
          float iou = inter / (sAR[ii] + ba - inter + 1e-9f);
          if (lane > i && iou > 0.5f) kp = false;
        }
        alive = __ballot(kp);
      }
      keepL[idx] = kp ? 1 : 0;
    }
    __syncthreads();
    if (t >= (tile+1)*64) {
      bool kp = keepL[t] != 0;
      if (kp) {
        #pragma unroll 1
        for (int i = tile*64; i < tile*64 + 64; i++) {
          if (keepL[i]) {
            float ltx = fmaxf(sX1[i], ox1), lty = fmaxf(sY1[i], oy1);
            float rbx = fminf(sX2[i], ox2), rby = fminf(sY2[i], oy2);
            float iw = fmaxf(rbx - ltx, 0.f), ih = fmaxf(rby - lty, 0.f);
            float inter = iw * ih;
            float iou = inter / (sAR[i] + area - inter + 1e-9f);
            if (iou > 0.5f) { kp = false; }
          }
        }
        if (!kp) keepL[t] = 0;
      }
    }
    __syncthreads();
  }

  bool keep = keepL[t] != 0;
  u64 bal = __ballot(keep);
  int wpre = __popcll(bal & ((1ull << lane) - 1ull));
  if (lane == 0) wsum[wid] = __popcll(bal);
  __syncthreads();
  int offn = 0, KT = 0;
  for (int q = 0; q < 16; q++) {
    int v = wsum[q];
    if (q < wid) offn += v;
    KT += v;
  }
  int rank = offn + wpre;
  float* outB = out;
  float* outS = out + 1600;
  float* outL = out + 2000;
  if (keep && rank < 100) {
    size_t s = (size_t)b*100 + rank;
    outB[s*4+0] = cb0; outB[s*4+1] = cb1;
    outB[s*4+2] = cb2; outB[s*4+3] = cb3;
    outS[s] = score; outL[s] = (float)label;
  }
  if (t < 100 && t >= KT) {
    size_t s = (size_t)b*100 + t;
    outB[s*4+0] = 0.f; outB[s*4+1] = 0.f; outB[s*4+2] = 0.f; outB[s*4+3] = 0.f;
    outS[s] = 0.f; outL[s] = 0.f;
  }
}

extern "C" void kernel_launch(void* const* d_in, const int* in_sizes, int n_in,
                              void* d_out, int out_size, void* d_ws, size_t ws_size,
                              hipStream_t stream) {
  (void)in_sizes; (void)n_in; (void)out_size; (void)ws_size;
  const float* feat  = (const float*)d_in[0];
  const float* props = (const float*)d_in[1];
  const float* W6 = (const float*)d_in[2];
  const float* b6 = (const float*)d_in[3];
  const float* W7 = (const float*)d_in[4];
  const float* b7 = (const float*)d_in[5];
  const float* Wc = (const float*)d_in[6];
  const float* bc = (const float*)d_in[7];
  const float* Wb = (const float*)d_in[8];
  const float* bb = (const float*)d_in[9];
  float* out = (float*)d_out;
  char* ws = (char*)d_ws;

  float* featT  = (float*)(ws);                        // 62,259,200 B
  u16*   Xs2    = (u16*)  (ws + 62259200);             // 51,380,224 B (tiled)
  float* part   = (float*)(ws);                        // 33,554,432 B (8 slices)
  u16*   Y1s2   = (u16*)  (ws + 33554432);             //  4,194,304 B (tiled)
  u16*   Y2s2   = (u16*)  (ws + 37748736);             //  4,194,304 B (tiled)
  u16*   W7t    = (u16*)  (ws + 41943040);             //  4,194,304 B (tiled B)
  u16*   Wcatt  = (u16*)  (ws + 46137344);             //  2,097,152 B (tiled B)
  float* bcat   = (float*)(ws + 48234496);             //      2,048 B
  float* cboxes = (float*)(ws + 50102272);             //  1,474,560 B
  u64*   keys   = (u64*)  (ws + 51576832);             //    737,280 B
  u64*   sorted = (u64*)  (ws + 52314112);             //     65,536 B

  dim3 gT(475, 8, 4);
  k_transpose<<<gT, 256, 0, stream>>>(feat, featT);
  k_roialign<<<1024, 256, 0, stream>>>(featT, props, Xs2);
  // packs (outputs live in dead-featT region -> must run after roialign)
  k_packs<<<768, 256, 0, stream>>>(W7, W7t, Wc, Wb, bc, bb, Wcatt, bcat);

  // FC6: 128x256 tiles (8x4=32) x split-K 8 = 256 blocks (1/CU), 49 steps
  k_gemm_fc6<<<256, 512, 0, stream>>>(Xs2, W6, part, DIN/8, 49);
  k_reduce_split<<<512, 256, 0, stream>>>(part, b6, Y1s2);
  // FC7: K=1024, split-K=8, 4 steps/slice, fp16-B path
  k_gemm_f16b<<<512, 512, 0, stream>>>(Y1s2, W7t, part, 128, 128, 4, 8, 1024, 1048576);
  k_reduce_split<<<512, 256, 0, stream>>>(part, b7, Y2s2);
  // heads: M=1024, N=512(padded 455), K=1024, split-K=8, fp16-B path
  k_gemm_f16b<<<256, 512, 0, stream>>>(Y2s2, Wcatt, part, 128, 128, 4, 4, 512, 524288);
  // fused heads-finish (sum + bias + softmax + decode + keys)
  k_headfin<<<1024, 128, 0, stream>>>(part, bcat, props, cboxes, keys);

  k_sort<<<8, 1024, 0, stream>>>(keys, sorted);
  k_nms<<<4, 1024, 0, stream>>>(sorted, cboxes, out);
}

// Round 15
// 336.429 us; speedup vs baseline: 1.0846x; 1.0018x over previous
//
#include <hip/hip_runtime.h>
#include <hip/hip_bf16.h>
#include <stdint.h>

#define B_    4
#define N_    256
#define C_    256
#define FH_   100
#define FW_   152
#define P_HW  (FH_*FW_)      // 15200
#define NCLS  91
#define CAND  23040          // N_*90
#define DIN   12544
#define PRE   1024

typedef unsigned long long u64;
typedef unsigned int u32;
typedef unsigned short u16;
typedef __attribute__((ext_vector_type(8))) _Float16 half8;
typedef __attribute__((ext_vector_type(8))) short short8;
typedef __attribute__((ext_vector_type(4))) float f32x4;

__device__ inline u16 h2bits(_Float16 h) { return *reinterpret_cast<u16*>(&h); }

__device__ inline void split2(float v, u16& b0, u16& b1) {
  _Float16 h0 = (_Float16)v;
  float r = v - (float)h0;
  _Float16 h1 = (_Float16)r;
  b0 = h2bits(h0); b1 = h2bits(h1);
}

__device__ inline void gload_lds16(const void* g, void* l) {
  __builtin_amdgcn_global_load_lds(
      (const __attribute__((address_space(1))) void*)g,
      (__attribute__((address_space(3))) void*)l, 16, 0, 0);
}

// ---------------- feature transpose (B,C,H,W) -> (B,H,W,C) ----------------
__global__ void k_transpose(const float* __restrict__ in, float* __restrict__ out) {
  __shared__ float t[32][33];
  int b  = blockIdx.z;
  int c0 = blockIdx.y * 32;
  int p0 = blockIdx.x * 32;
  int tx = threadIdx.x & 31, ty = threadIdx.x >> 5;
  const float* inb = in  + (size_t)b * C_ * P_HW;
  float*       ob  = out + (size_t)b * P_HW * C_;
  #pragma unroll
  for (int q = 0; q < 4; q++)
    t[ty + q*8][tx] = inb[(size_t)(c0 + ty + q*8) * P_HW + p0 + tx];
  __syncthreads();
  #pragma unroll
  for (int q = 0; q < 4; q++)
    ob[(size_t)(p0 + ty + q*8) * C_ + c0 + tx] = t[tx][ty + q*8];
}

// -------- packs: W7 (blocks 0..511) + heads Wc|Wb (512..767) ---------------
__global__ void k_packs(const float* __restrict__ W7, u16* __restrict__ W7t,
                        const float* __restrict__ Wc, const float* __restrict__ Wb,
                        const float* __restrict__ bc, const float* __restrict__ bb,
                        u16* __restrict__ Wcatt, float* __restrict__ bcat) {
  int bid = blockIdx.x;
  int tid = threadIdx.x;
  if (bid < 512) {
    int idx = bid * 256 + tid;                 // 131072 = 128 ko x 1024 col
    int col = idx & 1023, ko = idx >> 10;
    short8 c0v, c1v;
    #pragma unroll
    for (int e = 0; e < 8; e++) {
      float w = W7[(size_t)(ko*8 + e)*1024 + col] * 128.0f;
      u16 h0, h1;
      split2(w, h0, h1);
      c0v[e] = (short)h0; c1v[e] = (short)h1;
    }
    *reinterpret_cast<short8*>(W7t + ((size_t)ko*1024 + col)*8)         = c0v;
    *reinterpret_cast<short8*>(W7t + ((size_t)(128 + ko)*1024 + col)*8) = c1v;
  } else {
    int idx = (bid - 512) * 256 + tid;         // 65536 = 128 ko x 512 col
    int col = idx & 511, ko = idx >> 9;
    short8 c0v, c1v;
    #pragma unroll
    for (int e = 0; e < 8; e++) {
      int k = ko*8 + e;
      float w = 0.f;
      if (col < 91)       w = Wc[(size_t)k*91 + col];
      else if (col < 455) w = Wb[(size_t)k*364 + (col - 91)];
      w *= 128.0f;
      u16 h0, h1;
      split2(w, h0, h1);
      c0v[e] = (short)h0; c1v[e] = (short)h1;
    }
    *reinterpret_cast<short8*>(Wcatt + ((size_t)ko*512 + col)*8)         = c0v;
    *reinterpret_cast<short8*>(Wcatt + ((size_t)(128 + ko)*512 + col)*8) = c1v;
    if (idx < 512) {
      float bv = 0.f;
      if (idx < 91)       bv = bc[idx];
      else if (idx < 455) bv = bb[idx - 91];
      bcat[idx] = bv;
    }
  }
}

// ------- roi align -> Xt [2 planes][DIN/8][1024 rows][8] fp16 of (X*16) ----
__global__ __launch_bounds__(256, 8) void k_roialign(const float* __restrict__ featT,
                                                     const float* __restrict__ props,
                                                     u16* __restrict__ Xs) {
  __shared__ float sPW[196][8];     // {p00,p01,p10,p11,w00,w01,w10,w11}
  __shared__ float cellv[32][51];   // [ch-in-group][cell]
  int bid = blockIdx.x;
  int xcd = bid & 7;
  int b = xcd >> 1;
  int n = ((bid >> 3) << 1) | (xcd & 1);
  int r = (b << 8) | n;                 // bijective 0..1023, XCD-batch affine
  int tid = threadIdx.x;

  float x1 = props[r*4+0], y1 = props[r*4+1];
  float x2 = props[r*4+2], y2 = props[r*4+3];
  float x1s = x1 * 0.125f, y1s = y1 * 0.125f;
  float x2s = x2 * 0.125f, y2s = y2 * 0.125f;
  float rw = fmaxf(x2s - x1s, 1.0f);
  float rh = fmaxf(y2s - y1s, 1.0f);
  float rwd = rw / 7.0f, rhd = rh / 7.0f;

  if (tid < 196) {
    int cell = tid >> 2, s = tid & 3;
    int py = cell / 7, px = cell % 7;
    int sy = s >> 1, sx = s & 1;
    float gqy = (float)py + 0.25f + 0.5f * (float)sy;
    float gqx = (float)px + 0.25f + 0.5f * (float)sx;
    float gy = fminf(fmaxf(y1s + rhd * gqy, 0.0f), 99.0f);
    float gx = fminf(fmaxf(x1s + rwd * gqx, 0.0f), 151.0f);
    float y0f = floorf(gy), x0f = floorf(gx);
    float ly = gy - y0f, lx = gx - x0f;
    int y0i = (int)y0f;
    int y1i = (int)fminf(y0f + 1.0f, 99.0f);
    int x0i = (int)x0f;
    int x1i = (int)fminf(x0f + 1.0f, 151.0f);
    sPW[tid][0] = __int_as_float((y0i * FW_ + x0i) * 256);
    sPW[tid][1] = __int_as_float((y0i * FW_ + x1i) * 256);
    sPW[tid][2] = __int_as_float((y1i * FW_ + x0i) * 256);
    sPW[tid][3] = __int_as_float((y1i * FW_ + x1i) * 256);
    sPW[tid][4] = (1.f-ly)*(1.f-lx);
    sPW[tid][5] = (1.f-ly)*lx;
    sPW[tid][6] = ly*(1.f-lx);
    sPW[tid][7] = ly*lx;
  }
  __syncthreads();

  int c32 = tid & 31;
  int slot = tid >> 5;
  const size_t PLS = (size_t)(DIN/8) * 1024 * 8;

  for (int g = 0; g < 8; g++) {
    const float* fb = featT + (size_t)b * P_HW * C_ + g*32 + c32;
    for (int cell = slot; cell < 49; cell += 8) {
      float acc = 0.f;
      #pragma unroll
      for (int s = 0; s < 4; s++) {
        int cs = cell*4 + s;
        float4 pv = *(const float4*)&sPW[cs][0];
        float4 wv = *(const float4*)&sPW[cs][4];
        acc += wv.x * fb[__float_as_int(pv.x)]
             + wv.y * fb[__float_as_int(pv.y)]
             + wv.z * fb[__float_as_int(pv.z)]
             + wv.w * fb[__float_as_int(pv.w)];
      }
      cellv[c32][cell] = acc * 4.0f;   // 0.25 (avg) * 16 (prescale)
    }
    __syncthreads();
    if (tid < 196) {
      short8 v0, v1;
      #pragma unroll
      for (int e = 0; e < 8; e++) {
        int kl = tid*8 + e;
        int chl = kl / 49;
        int cell = kl - chl*49;
        float v = cellv[chl][cell];
        u16 h0, h1;
        split2(v, h0, h1);
        v0[e] = (short)h0; v1[e] = (short)h1;
      }
      size_t cg = (size_t)g*196 + tid;
      size_t base = (cg * 1024 + r) * 8;
      *reinterpret_cast<short8*>(Xs + base)       = v0;
      *reinterpret_cast<short8*>(Xs + PLS + base) = v1;
    }
    __syncthreads();
  }
}

// -------- FC6 MFMA GEMM: 128x256 tile, single-barrier 3-buffer pipeline ----
// fp32 via fp16 2-plane 3-pass. 8 waves, wave tile 128x32 (fr=8, fc=2).
// Counted-vmcnt placed BEFORE the barrier: each wave drains its OWN stage-s
// loads (vmcnt(6)), then the barrier publishes ALL waves' stage-s LDS writes
// -> formally race-free. Stage s+1 stays in flight across the barrier;
// stage s+2 issues after the barrier and overlaps compute.
__global__ __launch_bounds__(512) void k_gemm_fc6(
    const u16* __restrict__ As, const float* __restrict__ Bw,
    float* __restrict__ part, int kg, int nsteps) {
  __shared__ __align__(16) char lds[147456];   // 3 x (A 16KB + B 32KB)
  int tid = threadIdx.x;
  int wid = tid >> 6, lane = tid & 63;
  int l15 = lane & 15, lq = lane >> 4;
  int bid = blockIdx.x;
  int z = bid & 7, xy = bid >> 3;              // one K-slice per XCD
  int col0 = (xy & 3) * 256, row0 = (xy >> 2) * 128;
  int kbase0 = z * nsteps * 32;

  auto STAGE = [&](int s, int bsel) {
    int kb = kbase0 + s * 32;
    char* dst = lds + (size_t)bsel * 49152;
    #pragma unroll
    for (int j = 0; j < 6; j++) {
      int cid = tid + j*512;
      const char* src;
      if (j < 2) {
        // A: 1024 chunks = [2 pl][4 kc][128 rows]
        int pl = cid >> 9;
        int kc = (cid >> 7) & 3, rr = cid & 127;
        src = (const char*)(As + ((size_t)(pl*kg + (kb>>3) + kc)*1024 + row0 + rr)*8);
      } else {
        // B: 2048 chunks = [32 k][64 col-chunks of 4 f32], XOR-swizzled
        int cid2 = cid - 1024;
        int kk = cid2 >> 6, c4 = cid2 & 63;
        int col = (c4*4) ^ (((kk >> 3) & 1) << 4);
        src = (const char*)(Bw + (size_t)(kb + kk)*1024 + col0 + col);
      }
      gload_lds16(src, dst + (size_t)cid*16);
    }
  };

  f32x4 acc[8][2];
  #pragma unroll
  for (int i = 0; i < 8; i++)
    #pragma unroll
    for (int j = 0; j < 2; j++)
      #pragma unroll
      for (int q = 0; q < 4; q++) acc[i][j][q] = 0.f;

  STAGE(0, 0);
  if (nsteps > 1) STAGE(1, 1);
  int rb = 0, tb = 2;                          // read-buf, stage-target buf
  for (int s = 0; s < nsteps; s++) {
    // drain OWN stage-s loads, keep stage s+1 in flight; then barrier
    // publishes ALL waves' stage-s LDS writes (formal RAW fence).
    __builtin_amdgcn_sched_barrier(0);
    if (s + 1 < nsteps) asm volatile("s_waitcnt vmcnt(6)" ::: "memory");
    else                asm volatile("s_waitcnt vmcnt(0)" ::: "memory");
    __builtin_amdgcn_s_barrier();
    __builtin_amdgcn_sched_barrier(0);
    // WAR-safe: buf tb was read at step s-1; all waves passed that compute
    // (reads retired) before arriving at this barrier.
    if (s + 2 < nsteps) STAGE(s + 2, tb);

    const u16*   Alds = (const u16*)(lds + (size_t)rb * 49152);
    const float* Blds = (const float*)(lds + (size_t)rb * 49152 + 16384);

    // A fragments: whole 128-row panel (2 planes x 8 row-frags)
    half8 af[2][8];
    #pragma unroll
    for (int pl = 0; pl < 2; pl++)
      #pragma unroll
      for (int fr = 0; fr < 8; fr++) {
        int chunk = (pl*4 + lq)*128 + fr*16 + l15;
        af[pl][fr] = *reinterpret_cast<const half8*>(&Alds[(size_t)chunk*8]);
      }
    int cxor = (lq & 1) << 4;
    __builtin_amdgcn_s_setprio(1);
    #pragma unroll
    for (int fc = 0; fc < 2; fc++) {
      int colx = (wid*32 + fc*16 + l15) ^ cxor;
      half8 b0, b1;
      #pragma unroll
      for (int j = 0; j < 8; j++) {
        float w = Blds[(lq*8 + j)*256 + colx] * 128.0f;
        _Float16 h0 = (_Float16)w;
        float rres = w - (float)h0;
        b0[j] = h0; b1[j] = (_Float16)rres;
      }
      #pragma unroll
      for (int fr = 0; fr < 8; fr++) {
        acc[fr][fc] = __builtin_amdgcn_mfma_f32_16x16x32_f16(af[0][fr], b0, acc[fr][fc], 0, 0, 0);
        acc[fr][fc] = __builtin_amdgcn_mfma_f32_16x16x32_f16(af[1][fr], b0, acc[fr][fc], 0, 0, 0);
        acc[fr][fc] = __builtin_amdgcn_mfma_f32_16x16x32_f16(af[0][fr], b1, acc[fr][fc], 0, 0, 0);
      }
    }
    __builtin_amdgcn_s_setprio(0);
    __builtin_amdgcn_sched_barrier(0);
    rb = (rb == 2) ? 0 : rb + 1;
    tb = (tb == 2) ? 0 : tb + 1;
  }

  float* pp = part + (size_t)z * 1048576;
  #pragma unroll
  for (int fr = 0; fr < 8; fr++)
    #pragma unroll
    for (int fc = 0; fc < 2; fc++) {
      int col = col0 + wid*32 + fc*16 + l15;
      #pragma unroll
      for (int rr = 0; rr < 4; rr++) {
        int row = row0 + fr*16 + lq*4 + rr;
        pp[(size_t)row*1024 + col] = acc[fr][fc][rr];
      }
    }
}

// -------- MFMA GEMM, pre-split fp16 2-plane B (FC7 / heads) ---------------
__global__ __launch_bounds__(512) void k_gemm_f16b(
    const u16* __restrict__ As, const u16* __restrict__ Bt,
    float* __restrict__ part, int kgA, int kgB, int nsteps, int nct, int outw,
    size_t sstride) {
  __shared__ __align__(16) char lds[65536];
  int tid = threadIdx.x;
  int wid = tid >> 6, lane = tid & 63;
  int l15 = lane & 15, lq = lane >> 4;
  int bid = blockIdx.x;
  int z = bid & 7, xy = bid >> 3;
  int col0 = (xy % nct) * 128, row0 = (xy / nct) * 128;
  int wr = wid >> 2, wc = wid & 3;
  int kbase0 = z * nsteps * 32;

  auto STAGE = [&](int s, int bsel) {
    int kb = kbase0 + s * 32;
    char* dst = lds + bsel * 32768;
    #pragma unroll
    for (int j = 0; j < 4; j++) {
      int cid = tid + j*512;
      const char* src;
      if (j < 2) {
        int pl = cid >> 9;
        int kc = (cid >> 7) & 3, rr = cid & 127;
        src = (const char*)(As + ((size_t)(pl*kgA + (kb>>3) + kc)*1024 + row0 + rr)*8);
      } else {
        int cid2 = cid - 1024;
        int pl = cid2 >> 9;
        int kc = (cid2 >> 7) & 3, cc = cid2 & 127;
        src = (const char*)(Bt + ((size_t)(pl*kgB + (kb>>3) + kc)*outw + col0 + cc)*8);
      }
      gload_lds16(src, dst + (size_t)cid*16);
    }
  };

  f32x4 acc[4][2];
  #pragma unroll
  for (int i = 0; i < 4; i++)
    #pragma unroll
    for (int j = 0; j < 2; j++)
      #pragma unroll
      for (int q = 0; q < 4; q++) acc[i][j][q] = 0.f;

  STAGE(0, 0);
  for (int s = 0; s < nsteps; s++) {
    int cur = s & 1;
    if (s + 1 < nsteps) {
      STAGE(s + 1, cur ^ 1);
      asm volatile("s_waitcnt vmcnt(4)" ::: "memory");
    } else {
      asm volatile("s_waitcnt vmcnt(0)" ::: "memory");
    }
    __builtin_amdgcn_s_barrier();
    __builtin_amdgcn_sched_barrier(0);

    const u16* Alds = (const u16*)(lds + cur * 32768);
    const u16* Blds = (const u16*)(lds + cur * 32768 + 16384);

    half8 af[2][4];
    #pragma unroll
    for (int pl = 0; pl < 2; pl++)
      #pragma unroll
      for (int fr = 0; fr < 4; fr++) {
        int chunk = (pl*4 + lq)*128 + wr*64 + fr*16 + l15;
        af[pl][fr] = *reinterpret_cast<const half8*>(&Alds[(size_t)chunk*8]);
      }
    #pragma unroll
    for (int fc = 0; fc < 2; fc++) {
      int cc = wc*32 + fc*16 + l15;
      half8 b0 = *reinterpret_cast<const half8*>(&Blds[(size_t)((0*4 + lq)*128 + cc)*8]);
      half8 b1 = *reinterpret_cast<const half8*>(&Blds[(size_t)((1*4 + lq)*128 + cc)*8]);
      #pragma unroll
      for (int fr = 0; fr < 4; fr++) {
        acc[fr][fc] = __builtin_amdgcn_mfma_f32_16x16x32_f16(af[0][fr], b0, acc[fr][fc], 0, 0, 0);
        acc[fr][fc] = __builtin_amdgcn_mfma_f32_16x16x32_f16(af[1][fr], b0, acc[fr][fc], 0, 0, 0);
        acc[fr][fc] = __builtin_amdgcn_mfma_f32_16x16x32_f16(af[0][fr], b1, acc[fr][fc], 0, 0, 0);
      }
    }
    __builtin_amdgcn_sched_barrier(0);
    asm volatile("s_waitcnt lgkmcnt(0)" ::: "memory");
    __builtin_amdgcn_s_barrier();
  }

  float* pp = part + (size_t)z * sstride;
  #pragma unroll
  for (int fr = 0; fr < 4; fr++)
    #pragma unroll
    for (int fc = 0; fc < 2; fc++) {
      int col = col0 + wc*32 + fc*16 + l15;
      #pragma unroll
      for (int rr = 0; rr < 4; rr++) {
        int row = row0 + wr*64 + fr*16 + lq*4 + rr;
        pp[(size_t)row*outw + col] = acc[fr][fc][rr];
      }
    }
}

// -------- reduce split-K -> tiled fp16 planes --------------------------------
__global__ void k_reduce_split(const float* __restrict__ part,
                               const float* __restrict__ bias,
                               u16* __restrict__ ys) {
  int idx = blockIdx.x * 256 + threadIdx.x;
  int row = idx >> 7, cg = idx & 127;
  float4 s0 = {0,0,0,0}, s1 = {0,0,0,0};
  #pragma unroll
  for (int s = 0; s < 8; s++) {
    const float4* p = (const float4*)(part + (size_t)s*1048576 + (size_t)row*1024 + cg*8);
    float4 a = p[0], b = p[1];
    s0.x += a.x; s0.y += a.y; s0.z += a.z; s0.w += a.w;
    s1.x += b.x; s1.y += b.y; s1.z += b.z; s1.w += b.w;
  }
  float v[8] = {s0.x, s0.y, s0.z, s0.w, s1.x, s1.y, s1.z, s1.w};
  short8 o0, o1;
  #pragma unroll
  for (int e = 0; e < 8; e++) {
    float x = v[e] * (1.0f/2048.0f) + bias[cg*8 + e];
    x = fmaxf(x, 0.f) * 16.0f;
    u16 h0, h1;
    split2(x, h0, h1);
    o0[e] = (short)h0; o1[e] = (short)h1;
  }
  size_t base = ((size_t)cg * 1024 + row) * 8;
  *reinterpret_cast<short8*>(ys + base)               = o0;
  *reinterpret_cast<short8*>(ys + (size_t)1048576 + base) = o1;
}

// -------- fused heads finish: sum part + bias + softmax + decode + keys ----
__global__ __launch_bounds__(128) void k_headfin(const float* __restrict__ part,
                                                 const float* __restrict__ bcat,
                                                 const float* __restrict__ props,
                                                 float* __restrict__ cboxes,
                                                 u64* __restrict__ keys) {
  __shared__ float sc[512];
  __shared__ float red[128];
  int r = blockIdx.x;
  int j = threadIdx.x;
  int c0 = j * 4;
  float4 v = {0.f, 0.f, 0.f, 0.f};
  #pragma unroll
  for (int s = 0; s < 8; s++) {
    float4 p = *(const float4*)(part + (size_t)s*524288 + (size_t)r*512 + c0);
    v.x += p.x; v.y += p.y; v.z += p.z; v.w += p.w;
  }
  float4 bz = *(const float4*)(bcat + c0);
  sc[c0+0] = v.x * (1.0f/2048.0f) + bz.x;
  sc[c0+1] = v.y * (1.0f/2048.0f) + bz.y;
  sc[c0+2] = v.z * (1.0f/2048.0f) + bz.z;
  sc[c0+3] = v.w * (1.0f/2048.0f) + bz.w;
  __syncthreads();

  float lg = (j < NCLS) ? sc[j] : -3.4e38f;
  red[j] = lg;
  __syncthreads();
  for (int s = 64; s > 0; s >>= 1) {
    if (j < s) red[j] = fmaxf(red[j], red[j+s]);
    __syncthreads();
  }
  float mx = red[0];
  __syncthreads();
  float e = (j < NCLS) ? expf(lg - mx) : 0.f;
  red[j] = e;
  __syncthreads();
  for (int s = 64; s > 0; s >>= 1) {
    if (j < s) red[j] += red[j+s];
    __syncthreads();
  }
  float p = e / red[0];
  if (j >= 1 && j < NCLS) {
    float px1 = props[r*4+0], py1 = props[r*4+1];
    float px2 = props[r*4+2], py2 = props[r*4+3];
    float w = px2 - px1, h = py2 - py1;
    float cx = px1 + 0.5f*w, cy = py1 + 0.5f*h;
    float d0 = sc[91 + j*4 + 0];
    float d1 = sc[91 + j*4 + 1];
    float d2 = sc[91 + j*4 + 2];
    float d3 = sc[91 + j*4 + 3];
    float dx = d0 / 10.0f, dy = d1 / 10.0f;
    float dw = fminf(d2 / 5.0f, 4.135166556742356f);
    float dh = fminf(d3 / 5.0f, 4.135166556742356f);
    float pcx = dx*w + cx, pcy = dy*h + cy;
    float pw = expf(dw)*w, ph = expf(dh)*h;
    float bx1 = fminf(fmaxf(pcx - 0.5f*pw, 0.f), 1216.f);
    float by1 = fminf(fmaxf(pcy - 0.5f*ph, 0.f),  800.f);
    float bx2 = fminf(fmaxf(pcx + 0.5f*pw, 0.f), 1216.f);
    float by2 = fminf(fmaxf(pcy + 0.5f*ph, 0.f),  800.f);
    bool valid = (p > 0.05f) && ((bx2 - bx1) >= 0.01f) && ((by2 - by1) >= 0.01f);
    int b = r >> 8, n = r & 255;
    int cidx = n*90 + (j-1);
    size_t cb = (size_t)b*CAND + cidx;
    cboxes[cb*4+0] = bx1; cboxes[cb*4+1] = by1;
    cboxes[cb*4+2] = bx2; cboxes[cb*4+3] = by2;
    u64 key = 0ull;
    if (valid)
      key = (((u64)__float_as_uint(p)) << 32) | (u32)(~(u32)cidx);
    keys[cb] = key;
  }
}

// -------- per (batch,half): compact valid + bitonic sort desc, top1024 -----
#define SORTN 4096
__global__ __launch_bounds__(1024) void k_sort(const u64* __restrict__ keys,
                                               u64* __restrict__ sorted) {
  __shared__ u64 sk[SORTN];
  __shared__ int cnt;
  int t = threadIdx.x;
  int b = blockIdx.x >> 1, h = blockIdx.x & 1;
  if (t == 0) cnt = 0;
  __syncthreads();
  const u64* kb = keys + (size_t)b*CAND + (size_t)h*(CAND/2);
  for (int q = 0; q < 12; q++) {
    int idx = t + q*1024;
    if (idx < CAND/2) {
      u64 k = kb[idx];
      if (k) { int pos = atomicAdd(&cnt, 1); sk[pos] = k; }
    }
  }
  __syncthreads();
  int total = cnt;
  for (int s = t; s < SORTN; s += 1024)
    if (s >= total) sk[s] = 0ull;
  __syncthreads();
  for (int k = 2; k <= SORTN; k <<= 1) {
    for (int jj = k >> 1; jj > 0; jj >>= 1) {
      for (int i = t; i < SORTN; i += 1024) {
        int ixj = i ^ jj;
        if (ixj > i) {
          u64 a = sk[i], bb = sk[ixj];
          bool up = ((i & k) == 0);
          if (up ? (a < bb) : (a > bb)) { sk[i] = bb; sk[ixj] = a; }
        }
      }
      __syncthreads();
    }
  }
  sorted[((size_t)b*2 + h)*1024 + t] = sk[t];
}

// -------- per batch: merge halves, tiled greedy NMS, emit final 100 --------
__global__ __launch_bounds__(1024) void k_nms(const u64* __restrict__ sorted,
                                              const float* __restrict__ cboxes,
                                              float* __restrict__ out) {
  __shared__ u64 m[2048];
  __shared__ float sX1[1024], sY1[1024], sX2[1024], sY2[1024], sAR[1024];
  __shared__ int keepL[1024];
  __shared__ int wsum[16];
  int t = threadIdx.x;
  int b = blockIdx.x;
  m[t]        = sorted[((size_t)b*2 + 0)*1024 + t];
  m[2047 - t] = sorted[((size_t)b*2 + 1)*1024 + t];
  __syncthreads();
  for (int lg = 10; lg >= 0; lg--) {
    int jj = 1 << lg;
    int pos = ((t >> lg) << (lg+1)) + (t & (jj-1));
    u64 a = m[pos], bb = m[pos + jj];
    if (a < bb) { m[pos] = bb; m[pos + jj] = a; }
    __syncthreads();
  }
  u64 key = m[t];
  bool valid = key != 0ull;
  float score = __uint_as_float((u32)(key >> 32));
  u32 cidx = ~((u32)(key & 0xFFFFFFFFu));
  int label = valid ? (int)(cidx % 90u) + 1 : 0;
  float cb0 = 0.f, cb1 = 0.f, cb2 = 0.f, cb3 = 0.f;
  if (valid) {
    size_t cb = ((size_t)b*CAND + cidx) * 4;
    cb0 = cboxes[cb+0]; cb1 = cboxes[cb+1];
    cb2 = cboxes[cb+2]; cb3 = cboxes[cb+3];
  }
  float off = (float)label * 1218.0f;
  float ox1 = cb0 + off, oy1 = cb1 + off;
  float ox2 = cb2 + off, oy2 = cb3 + off;
  float area = (ox2 - ox1) * (oy2 - oy1);
  sX1[t] = ox1; sY1[t] = oy1; sX2[t] = ox2; sY2[t] = oy2; sAR[t] = area;
  keepL[t] = valid ? 1 : 0;
  __syncthreads();

  int wid = t >> 6, lane = t & 63;
  for (int tile = 0; tile < 16; tile++) {
    if (wid == 0) {
      int idx = tile*64 + lane;
      bool kp = keepL[idx] != 0;
      float bx1 = sX1[idx], by1 = sY1[idx], bx2 = sX2[idx], by2 = sY2[idx], ba = sAR[idx];
      u64 alive = __ballot(kp);
      #pragma unroll 1
      for (int i = 0; i < 63; i++) {
        if ((alive >> i) & 1ull) {
          int ii = tile*64 + i;
          float ltx = fmaxf(sX1[ii], bx1), lty = fmaxf(sY1[ii], by1);
          float rbx = fminf(sX2[ii], bx2), rby = fminf(sY2[ii], by2);
          float iw = fmaxf(rbx - ltx, 0.f), ih = fmaxf(rby - lty, 0.f);
          float inter = iw * ih;
          float iou = inter / (sAR[ii] + ba - inter + 1e-9f);
          if (lane > i && iou > 0.5f) kp = false;
        }
        alive = __ballot(kp);
      }
      keepL[idx] = kp ? 1 : 0;
    }
    __syncthreads();
    if (t >= (tile+1)*64) {
      bool kp = keepL[t] != 0;
      if (kp) {
        #pragma unroll 1
        for (int i = tile*64; i < tile*64 + 64; i++) {
          if (keepL[i]) {
            float ltx = fmaxf(sX1[i], ox1), lty = fmaxf(sY1[i], oy1);
            float rbx = fminf(sX2[i], ox2), rby = fminf(sY2[i], oy2);
            float iw = fmaxf(rbx - ltx, 0.f), ih = fmaxf(rby - lty, 0.f);
            float inter = iw * ih;
            float iou = inter / (sAR[i] + area - inter + 1e-9f);
            if (iou > 0.5f) { kp = false; }
          }
        }
        if (!kp) keepL[t] = 0;
      }
    }
    __syncthreads();
  }

  bool keep = keepL[t] != 0;
  u64 bal = __ballot(keep);
  int wpre = __popcll(bal & ((1ull << lane) - 1ull));
  if (lane == 0) wsum[wid] = __popcll(bal);
  __syncthreads();
  int offn = 0, KT = 0;
  for (int q = 0; q < 16; q++) {
    int v = wsum[q];
    if (q < wid) offn += v;
    KT += v;
  }
  int rank = offn + wpre;
  float* outB = out;
  float* outS = out + 1600;
  float* outL = out + 2000;
  if (keep && rank < 100) {
    size_t s = (size_t)b*100 + rank;
    outB[s*4+0] = cb0; outB[s*4+1] = cb1;
    outB[s*4+2] = cb2; outB[s*4+3] = cb3;
    outS[s] = score; outL[s] = (float)label;
  }
  if (t < 100 && t >= KT) {
    size_t s = (size_t)b*100 + t;
    outB[s*4+0] = 0.f; outB[s*4+1] = 0.f; outB[s*4+2] = 0.f; outB[s*4+3] = 0.f;
    outS[s] = 0.f; outL[s] = 0.f;
  }
}

extern "C" void kernel_launch(void* const* d_in, const int* in_sizes, int n_in,
                              void* d_out, int out_size, void* d_ws, size_t ws_size,
                              hipStream_t stream) {
  (void)in_sizes; (void)n_in; (void)out_size; (void)ws_size;
  const float* feat  = (const float*)d_in[0];
  const float* props = (const float*)d_in[1];
  const float* W6 = (const float*)d_in[2];
  const float* b6 = (const float*)d_in[3];
  const float* W7 = (const float*)d_in[4];
  const float* b7 = (const float*)d_in[5];
  const float* Wc = (const float*)d_in[6];
  const float* bc = (const float*)d_in[7];
  const float* Wb = (const float*)d_in[8];
  const float* bb = (const float*)d_in[9];
  float* out = (float*)d_out;
  char* ws = (char*)d_ws;

  float* featT  = (float*)(ws);                        // 62,259,200 B
  u16*   Xs2    = (u16*)  (ws + 62259200);             // 51,380,224 B (tiled)
  float* part   = (float*)(ws);                        // 33,554,432 B (8 slices)
  u16*   Y1s2   = (u16*)  (ws + 33554432);             //  4,194,304 B (tiled)
  u16*   Y2s2   = (u16*)  (ws + 37748736);             //  4,194,304 B (tiled)
  u16*   W7t    = (u16*)  (ws + 41943040);             //  4,194,304 B (tiled B)
  u16*   Wcatt  = (u16*)  (ws + 46137344);             //  2,097,152 B (tiled B)
  float* bcat   = (float*)(ws + 48234496);             //      2,048 B
  float* cboxes = (float*)(ws + 50102272);             //  1,474,560 B
  u64*   keys   = (u64*)  (ws + 51576832);             //    737,280 B
  u64*   sorted = (u64*)  (ws + 52314112);             //     65,536 B

  dim3 gT(475, 8, 4);
  k_transpose<<<gT, 256, 0, stream>>>(feat, featT);
  k_roialign<<<1024, 256, 0, stream>>>(featT, props, Xs2);
  // packs (outputs live in dead-featT region -> must run after roialign)
  k_packs<<<768, 256, 0, stream>>>(W7, W7t, Wc, Wb, bc, bb, Wcatt, bcat);

  // FC6: 128x256 tiles (8x4=32) x split-K 8 = 256 blocks (1/CU), 49 steps
  k_gemm_fc6<<<256, 512, 0, stream>>>(Xs2, W6, part, DIN/8, 49);
  k_reduce_split<<<512, 256, 0, stream>>>(part, b6, Y1s2);
  // FC7: K=1024, split-K=8, 4 steps/slice, fp16-B path
  k_gemm_f16b<<<512, 512, 0, stream>>>(Y1s2, W7t, part, 128, 128, 4, 8, 1024, 1048576);
  k_reduce_split<<<512, 256, 0, stream>>>(part, b7, Y2s2);
  // heads: M=1024, N=512(padded 455), K=1024, split-K=8, fp16-B path
  k_gemm_f16b<<<256, 512, 0, stream>>>(Y2s2, Wcatt, part, 128, 128, 4, 4, 512, 524288);
  // fused heads-finish (sum + bias + softmax + decode + keys)
  k_headfin<<<1024, 128, 0, stream>>>(part, bcat, props, cboxes, keys);

  k_sort<<<8, 1024, 0, stream>>>(keys, sorted);
  k_nms<<<4, 1024, 0, stream>>>(sorted, cboxes, out);
}